// Round 5
// baseline (3123.954 us; speedup 1.0000x reference)
//
#include <hip/hip_runtime.h>

#define EMB 128
#define N_ITEMS 50000
#define N_SESS 50000
#define N_TOTAL 100000
#define NNZ_S 500000
#define NNZ_A 3200000
#define BATCH 2048
#define N_SCORE 50000

#define RPB 64                                 // rows per bucket
#define NB_A ((N_TOTAL + RPB - 1) / RPB)       // 1563
#define NB_S ((N_SESS + RPB - 1) / RPB)        // 782
#define NBMAX 1600
#define EPT 8
#define EPB (256 * EPT)                        // 2048 edges per block

typedef __attribute__((ext_vector_type(8))) short bf16x8;
typedef __attribute__((ext_vector_type(4))) float f32x4;

__device__ inline ushort f2bf(float f) {
    unsigned u = __float_as_uint(f);
    unsigned r = (u + 0x7fff + ((u >> 16) & 1)) >> 16;
    return (ushort)r;
}
__device__ inline float bflo(unsigned u) { return __uint_as_float(u << 16); }
__device__ inline float bfhi(unsigned u) { return __uint_as_float(u & 0xffff0000u); }

// ---------------- gather x_item = bf16(emb_table[item_emb_idxes]) ----------------
__global__ void k_gather_items_bf16(const float* __restrict__ emb, const int* __restrict__ idx,
                                    ushort* __restrict__ xb_item) {
    int t = blockIdx.x * blockDim.x + threadIdx.x;
    int i = t >> 5;
    int d = (t & 31) << 2;
    if (i >= N_ITEMS) return;
    float4 v = *(const float4*)(emb + (long)idx[i] * EMB + d);
    uint2 o;
    o.x = (unsigned)f2bf(v.x) | ((unsigned)f2bf(v.y) << 16);
    o.y = (unsigned)f2bf(v.z) | ((unsigned)f2bf(v.w) << 16);
    *(uint2*)(xb_item + (long)i * EMB + d) = o;
}

// ---------------- W -> Wt bf16 (transposed: Wt[n][k] = W[k][n]) ----------------
__global__ void k_convW(const float* __restrict__ W, ushort* __restrict__ Wt) {
    int i = blockIdx.x * 256 + threadIdx.x;
    if (i >= 128 * 128) return;
    int n = i >> 7, k = i & 127;
    Wt[n * 128 + k] = f2bf(W[k * 128 + n]);
}

// ---------------- bucket histogram: cnt[row>>6] += 1 (LDS-staged) ----------------
__global__ __launch_bounds__(256) void k_bucket_hist(const int* __restrict__ rows,
                                                     int* __restrict__ cnt, int nnz, int nb) {
    __shared__ int h[NBMAX];
    int tid = threadIdx.x;
    for (int i = tid; i < nb; i += 256) h[i] = 0;
    __syncthreads();
    long b0 = (long)blockIdx.x * EPB;
#pragma unroll
    for (int j = 0; j < EPT; ++j) {
        long e = b0 + j * 256 + tid;
        if (e < nnz) atomicAdd(&h[rows[e] >> 6], 1);
    }
    __syncthreads();
    for (int i = tid; i < nb; i += 256) {
        int v = h[i];
        if (v) atomicAdd(&cnt[i], v);
    }
}

// ---------------- single-block exclusive scan with carry (n <= ~2048 fast) ----------------
__global__ __launch_bounds__(1024) void k_scan_excl(const int* __restrict__ cnt,
                                                    int* __restrict__ off, int n) {
    __shared__ int wsum[16];
    __shared__ int carry_s;
    int tid = threadIdx.x, lane = tid & 63, wid = tid >> 6;
    if (tid == 0) carry_s = 0;
    __syncthreads();
    for (int base = 0; base < n; base += 1024) {
        int i = base + tid;
        int v = (i < n) ? cnt[i] : 0;
        int x = v;
#pragma unroll
        for (int s = 1; s < 64; s <<= 1) {
            int t = __shfl_up(x, s, 64);
            if (lane >= s) x += t;
        }
        if (lane == 63) wsum[wid] = x;
        __syncthreads();
        if (wid == 0) {
            int y = (lane < 16) ? wsum[lane] : 0;
#pragma unroll
            for (int s = 1; s < 16; s <<= 1) {
                int t = __shfl_up(y, s, 64);
                if (lane >= s) y += t;
            }
            if (lane < 16) wsum[lane] = y;
        }
        __syncthreads();
        int carry = carry_s;
        int wofs = (wid == 0) ? 0 : wsum[wid - 1];
        if (i < n) off[i] = carry + wofs + x - v;
        __syncthreads();
        if (tid == 0) carry_s = carry + wsum[15];
        __syncthreads();
    }
}

// ---------------- bucketed placement: dense per-bucket appends ----------------
// gtail starts as exclusive bucket offsets; advanced to inclusive ends.
// edge packed: key = (row & 63) << 17 | col   (col < 2^17), val as int bits
__global__ __launch_bounds__(256) void k_bucket_place(const int* __restrict__ rows,
                                                      const int* __restrict__ cols,
                                                      const float* __restrict__ vals,
                                                      int* __restrict__ gtail,
                                                      int2* __restrict__ out, int nnz, int nb) {
    __shared__ int h[NBMAX];
    __shared__ int base_s[NBMAX];
    int tid = threadIdx.x;
    for (int i = tid; i < nb; i += 256) h[i] = 0;
    __syncthreads();
    int er[EPT], ec[EPT];
    float ev[EPT];
    long b0 = (long)blockIdx.x * EPB;
#pragma unroll
    for (int j = 0; j < EPT; ++j) {
        long e = b0 + j * 256 + tid;
        if (e < nnz) {
            er[j] = rows[e];
            ec[j] = cols[e];
            ev[j] = vals[e];
            atomicAdd(&h[er[j] >> 6], 1);
        } else {
            er[j] = -1;
        }
    }
    __syncthreads();
    for (int i = tid; i < nb; i += 256) {
        int v = h[i];
        if (v) base_s[i] = atomicAdd(&gtail[i], v);
        h[i] = 0; // reuse as local cursor
    }
    __syncthreads();
#pragma unroll
    for (int j = 0; j < EPT; ++j) {
        if (er[j] >= 0) {
            int bk = er[j] >> 6;
            int loc = atomicAdd(&h[bk], 1);
            out[base_s[bk] + loc] = make_int2(((er[j] & 63) << 17) | ec[j], __float_as_int(ev[j]));
        }
    }
}

// ---------------- bucket SpMM: block per bucket, 64x128 fp32 acc in LDS ----------------
__global__ __launch_bounds__(512) void k_spmm_bucket(const int* __restrict__ gtail,
                                                     const int2* __restrict__ edges,
                                                     const ushort* __restrict__ src,
                                                     ushort* __restrict__ dst,
                                                     const float* __restrict__ bias,
                                                     int nrows) {
    __shared__ float acc[RPB * EMB]; // 32 KB
    int tid = threadIdx.x;
    int bk = blockIdx.x;
    for (int i = tid * 4; i < RPB * EMB; i += 512 * 4)
        *(float4*)(acc + i) = make_float4(0.f, 0.f, 0.f, 0.f);
    __syncthreads();
    int begin = bk ? gtail[bk - 1] : 0;
    int end = gtail[bk];
    int lane = tid & 63, w = tid >> 6;
    int e = begin + w;
    for (; e + 8 < end; e += 16) {
        int2 e0 = edges[e];
        int2 e1 = edges[e + 8];
        unsigned s0 = *(const unsigned*)(src + (long)(e0.x & 0x1FFFF) * EMB + lane * 2);
        unsigned s1 = *(const unsigned*)(src + (long)(e1.x & 0x1FFFF) * EMB + lane * 2);
        float v0 = __int_as_float(e0.y), v1 = __int_as_float(e1.y);
        int lr0 = e0.x >> 17, lr1 = e1.x >> 17;
        atomicAdd(&acc[lr0 * EMB + lane * 2],     v0 * bflo(s0));
        atomicAdd(&acc[lr0 * EMB + lane * 2 + 1], v0 * bfhi(s0));
        atomicAdd(&acc[lr1 * EMB + lane * 2],     v1 * bflo(s1));
        atomicAdd(&acc[lr1 * EMB + lane * 2 + 1], v1 * bfhi(s1));
    }
    if (e < end) {
        int2 e0 = edges[e];
        unsigned s0 = *(const unsigned*)(src + (long)(e0.x & 0x1FFFF) * EMB + lane * 2);
        float v0 = __int_as_float(e0.y);
        int lr0 = e0.x >> 17;
        atomicAdd(&acc[lr0 * EMB + lane * 2],     v0 * bflo(s0));
        atomicAdd(&acc[lr0 * EMB + lane * 2 + 1], v0 * bfhi(s0));
    }
    __syncthreads();
    // epilogue: thread -> (row, 16 dims)
    int lr = tid >> 3;
    int d0 = (tid & 7) * 16;
    int r = bk * RPB + lr;
    if (r < nrows) {
        unsigned o[8];
#pragma unroll
        for (int k = 0; k < 8; ++k) {
            float a = acc[lr * EMB + d0 + 2 * k];
            float c = acc[lr * EMB + d0 + 2 * k + 1];
            if (bias) {
                a += bias[d0 + 2 * k];
                c += bias[d0 + 2 * k + 1];
            }
            o[k] = (unsigned)f2bf(a) | ((unsigned)f2bf(c) << 16);
        }
        uint4* p = (uint4*)(dst + (long)r * EMB + d0);
        p[0] = make_uint4(o[0], o[1], o[2], o[3]);
        p[1] = make_uint4(o[4], o[5], o[6], o[7]);
    }
}

// ---------------- xw = xb @ Wt^T via MFMA (M=100000, N=128, K=128), bf16 out ----------------
__global__ __launch_bounds__(256) void k_xw_mfma(const ushort* __restrict__ A,
                                                 const ushort* __restrict__ Wt,
                                                 ushort* __restrict__ xw) {
    int wid = threadIdx.x >> 6;
    int lane = threadIdx.x & 63;
    int wm = wid >> 1, wn = wid & 1;
    long m0 = (long)blockIdx.x * 128 + wm * 64;
    int n0 = wn * 64;
    int r = lane & 15;
    int kg = lane >> 4;

    f32x4 acc[4][4] = {};
#pragma unroll
    for (int ks = 0; ks < 4; ++ks) {
        bf16x8 a[4], b[4];
#pragma unroll
        for (int mf = 0; mf < 4; ++mf) {
            long row = m0 + mf * 16 + r;
            if (row >= N_TOTAL) row = N_TOTAL - 1;
            a[mf] = *(const bf16x8*)(A + row * EMB + ks * 32 + kg * 8);
        }
#pragma unroll
        for (int nf = 0; nf < 4; ++nf) {
            int row = n0 + nf * 16 + r;
            b[nf] = *(const bf16x8*)(Wt + (long)row * EMB + ks * 32 + kg * 8);
        }
#pragma unroll
        for (int mf = 0; mf < 4; ++mf)
#pragma unroll
            for (int nf = 0; nf < 4; ++nf)
                acc[mf][nf] = __builtin_amdgcn_mfma_f32_16x16x32_bf16(a[mf], b[nf], acc[mf][nf], 0, 0, 0);
    }
#pragma unroll
    for (int mf = 0; mf < 4; ++mf) {
#pragma unroll
        for (int nf = 0; nf < 4; ++nf) {
            int col = n0 + nf * 16 + r;
#pragma unroll
            for (int j = 0; j < 4; ++j) {
                long row = m0 + mf * 16 + kg * 4 + j;
                if (row < N_TOTAL) xw[row * EMB + col] = f2bf(acc[mf][nf][j]);
            }
        }
    }
}

// ---------------- gather bf16 rows (256B row copy) ----------------
__global__ void k_gather_rows_bf16(const ushort* __restrict__ src, const int* __restrict__ idx,
                                   ushort* __restrict__ dst, int n) {
    int t = blockIdx.x * blockDim.x + threadIdx.x;
    int i = t >> 4;
    int d = (t & 15) << 3;
    if (i >= n) return;
    *(uint4*)(dst + (long)i * EMB + d) = *(const uint4*)(src + (long)idx[i] * EMB + d);
}

// ---------------- out[2048, 50000] = hb @ hi^T via MFMA bf16 ----------------
__global__ __launch_bounds__(256) void k_score_mfma(const ushort* __restrict__ A,
                                                    const ushort* __restrict__ B,
                                                    float* __restrict__ C) {
    int wid = threadIdx.x >> 6;
    int lane = threadIdx.x & 63;
    int wm = wid >> 1, wn = wid & 1;
    long m0 = (long)blockIdx.y * 128 + wm * 64;
    long n0 = (long)blockIdx.x * 128 + wn * 64;
    int r = lane & 15;
    int kg = lane >> 4;

    f32x4 acc[4][4] = {};
#pragma unroll
    for (int ks = 0; ks < 4; ++ks) {
        bf16x8 a[4], b[4];
#pragma unroll
        for (int mf = 0; mf < 4; ++mf) {
            long row = m0 + mf * 16 + r;
            a[mf] = *(const bf16x8*)(A + row * EMB + ks * 32 + kg * 8);
        }
#pragma unroll
        for (int nf = 0; nf < 4; ++nf) {
            long row = n0 + nf * 16 + r;
            if (row >= N_SCORE) row = N_SCORE - 1;
            b[nf] = *(const bf16x8*)(B + row * EMB + ks * 32 + kg * 8);
        }
#pragma unroll
        for (int mf = 0; mf < 4; ++mf)
#pragma unroll
            for (int nf = 0; nf < 4; ++nf)
                acc[mf][nf] = __builtin_amdgcn_mfma_f32_16x16x32_bf16(a[mf], b[nf], acc[mf][nf], 0, 0, 0);
    }
#pragma unroll
    for (int mf = 0; mf < 4; ++mf) {
#pragma unroll
        for (int nf = 0; nf < 4; ++nf) {
            long col = n0 + nf * 16 + r;
            if (col < N_SCORE) {
#pragma unroll
                for (int j = 0; j < 4; ++j) {
                    long row = m0 + mf * 16 + kg * 4 + j;
                    C[row * N_SCORE + col] = acc[mf][nf][j];
                }
            }
        }
    }
}

extern "C" void kernel_launch(void* const* d_in, const int* in_sizes, int n_in,
                              void* d_out, int out_size, void* d_ws, size_t ws_size,
                              hipStream_t stream) {
    const float* emb_table      = (const float*)d_in[0];
    const float* W              = (const float*)d_in[1];
    const float* b              = (const float*)d_in[2];
    const float* sess_vals      = (const float*)d_in[3];
    const float* A_vals         = (const float*)d_in[4];
    const int*   batch_idxes    = (const int*)d_in[5];
    const int*   item_idxes     = (const int*)d_in[6];
    const int*   item_emb_idxes = (const int*)d_in[7];
    const int*   sess_rows      = (const int*)d_in[8];
    const int*   sess_cols      = (const int*)d_in[9];
    const int*   A_rows         = (const int*)d_in[10];
    const int*   A_cols         = (const int*)d_in[11];
    float* out = (float*)d_out;

    // -------- workspace layout (bytes), ~120 MB --------
    char* base = (char*)d_ws;
    ushort* xb     = (ushort*)(base + 0);            // [N_TOTAL,128] bf16
    ushort* xw     = (ushort*)(base + 25600000L);    // [N_TOTAL,128] bf16
    ushort* h1     = (ushort*)(base + 51200000L);    // [N_TOTAL,128] bf16
    int2*   edgA   = (int2*)  (base + 76800000L);    // 3.2M x 8B bucketed
    int2*   edgS   = (int2*)  (base + 102400000L);   // 500K x 8B bucketed
    ushort* Wt     = (ushort*)(base + 106400000L);   // 128x128 bf16
    ushort* hb     = (ushort*)(base + 106432768L);   // [BATCH,128] bf16
    ushort* hi     = (ushort*)(base + 106957056L);   // [N_SCORE,128] bf16
    int*    cntBA  = (int*)   (base + 119757056L);   // NB_A
    int*    gtailA = (int*)   (base + 119763456L);   // NB_A
    int*    cntBS  = (int*)   (base + 119769856L);   // NB_S
    int*    gtailS = (int*)   (base + 119773056L);   // NB_S

    ushort* xb_item = xb + (long)N_SESS * EMB;

    // ---- session: bucket build ----
    hipMemsetAsync(cntBS, 0, NB_S * sizeof(int), stream);
    k_bucket_hist<<<(NNZ_S + EPB - 1) / EPB, 256, 0, stream>>>(sess_rows, cntBS, NNZ_S, NB_S);
    k_scan_excl<<<1, 1024, 0, stream>>>(cntBS, gtailS, NB_S);
    k_bucket_place<<<(NNZ_S + EPB - 1) / EPB, 256, 0, stream>>>(sess_rows, sess_cols, sess_vals,
                                                                gtailS, edgS, NNZ_S, NB_S);
    // ---- gather item embeddings (bf16) + W transpose ----
    k_gather_items_bf16<<<(N_ITEMS * 32 + 255) / 256, 256, 0, stream>>>(emb_table, item_emb_idxes, xb_item);
    k_convW<<<64, 256, 0, stream>>>(W, Wt);
    // ---- spmm1: session rows of xb ----
    k_spmm_bucket<<<NB_S, 512, 0, stream>>>(gtailS, edgS, xb_item, xb, nullptr, N_SESS);
    // ---- xw = xb @ W (MFMA) ----
    k_xw_mfma<<<(N_TOTAL + 127) / 128, 256, 0, stream>>>(xb, Wt, xw);
    // ---- A: bucket build ----
    hipMemsetAsync(cntBA, 0, NB_A * sizeof(int), stream);
    k_bucket_hist<<<(NNZ_A + EPB - 1) / EPB, 256, 0, stream>>>(A_rows, cntBA, NNZ_A, NB_A);
    k_scan_excl<<<1, 1024, 0, stream>>>(cntBA, gtailA, NB_A);
    k_bucket_place<<<(NNZ_A + EPB - 1) / EPB, 256, 0, stream>>>(A_rows, A_cols, A_vals,
                                                                gtailA, edgA, NNZ_A, NB_A);
    // ---- spmm2 + fused bias -> h1 (bf16) ----
    k_spmm_bucket<<<NB_A, 512, 0, stream>>>(gtailA, edgA, xw, h1, b, N_TOTAL);
    // ---- gather hb, hi ----
    k_gather_rows_bf16<<<(BATCH * 16 + 255) / 256, 256, 0, stream>>>(h1, batch_idxes, hb, BATCH);
    k_gather_rows_bf16<<<(N_SCORE * 16 + 255) / 256, 256, 0, stream>>>(h1, item_idxes, hi, N_SCORE);
    // ---- score ----
    dim3 grid((N_SCORE + 127) / 128, BATCH / 128);
    k_score_mfma<<<grid, 256, 0, stream>>>(hb, hi, out);
}

// Round 6
// 579.890 us; speedup vs baseline: 5.3872x; 5.3872x over previous
//
#include <hip/hip_runtime.h>

#define EMB 128
#define N_ITEMS 50000
#define N_SESS 50000
#define N_TOTAL 100000
#define NNZ_S 500000
#define NNZ_A 3200000
#define BATCH 2048
#define N_SCORE 50000

#define RPB 64                                 // rows per bucket
#define NB_A ((N_TOTAL + RPB - 1) / RPB)       // 1563
#define NB_S ((N_SESS + RPB - 1) / RPB)        // 782
#define NBMAX 1600
#define EPT 8
#define EPB (256 * EPT)                        // 2048 edges per block (build kernels)
#define CHUNK 4096                             // edges staged per sort pass

typedef __attribute__((ext_vector_type(8))) short bf16x8;
typedef __attribute__((ext_vector_type(4))) float f32x4;

__device__ inline ushort f2bf(float f) {
    unsigned u = __float_as_uint(f);
    unsigned r = (u + 0x7fff + ((u >> 16) & 1)) >> 16;
    return (ushort)r;
}
__device__ inline float bflo(unsigned u) { return __uint_as_float(u << 16); }
__device__ inline float bfhi(unsigned u) { return __uint_as_float(u & 0xffff0000u); }

// ---------------- gather x_item = bf16(emb_table[item_emb_idxes]) ----------------
__global__ void k_gather_items_bf16(const float* __restrict__ emb, const int* __restrict__ idx,
                                    ushort* __restrict__ xb_item) {
    int t = blockIdx.x * blockDim.x + threadIdx.x;
    int i = t >> 5;
    int d = (t & 31) << 2;
    if (i >= N_ITEMS) return;
    float4 v = *(const float4*)(emb + (long)idx[i] * EMB + d);
    uint2 o;
    o.x = (unsigned)f2bf(v.x) | ((unsigned)f2bf(v.y) << 16);
    o.y = (unsigned)f2bf(v.z) | ((unsigned)f2bf(v.w) << 16);
    *(uint2*)(xb_item + (long)i * EMB + d) = o;
}

// ---------------- W -> Wt bf16 (transposed: Wt[n][k] = W[k][n]) ----------------
__global__ void k_convW(const float* __restrict__ W, ushort* __restrict__ Wt) {
    int i = blockIdx.x * 256 + threadIdx.x;
    if (i >= 128 * 128) return;
    int n = i >> 7, k = i & 127;
    Wt[n * 128 + k] = f2bf(W[k * 128 + n]);
}

// ---------------- bucket histogram: cnt[row>>6] += 1 (LDS-staged) ----------------
__global__ __launch_bounds__(256) void k_bucket_hist(const int* __restrict__ rows,
                                                     int* __restrict__ cnt, int nnz, int nb) {
    __shared__ int h[NBMAX];
    int tid = threadIdx.x;
    for (int i = tid; i < nb; i += 256) h[i] = 0;
    __syncthreads();
    long b0 = (long)blockIdx.x * EPB;
#pragma unroll
    for (int j = 0; j < EPT; ++j) {
        long e = b0 + j * 256 + tid;
        if (e < nnz) atomicAdd(&h[rows[e] >> 6], 1);
    }
    __syncthreads();
    for (int i = tid; i < nb; i += 256) {
        int v = h[i];
        if (v) atomicAdd(&cnt[i], v);
    }
}

// ---------------- single-block exclusive scan with carry ----------------
__global__ __launch_bounds__(1024) void k_scan_excl(const int* __restrict__ cnt,
                                                    int* __restrict__ off, int n) {
    __shared__ int wsum[16];
    __shared__ int carry_s;
    int tid = threadIdx.x, lane = tid & 63, wid = tid >> 6;
    if (tid == 0) carry_s = 0;
    __syncthreads();
    for (int base = 0; base < n; base += 1024) {
        int i = base + tid;
        int v = (i < n) ? cnt[i] : 0;
        int x = v;
#pragma unroll
        for (int s = 1; s < 64; s <<= 1) {
            int t = __shfl_up(x, s, 64);
            if (lane >= s) x += t;
        }
        if (lane == 63) wsum[wid] = x;
        __syncthreads();
        if (wid == 0) {
            int y = (lane < 16) ? wsum[lane] : 0;
#pragma unroll
            for (int s = 1; s < 16; s <<= 1) {
                int t = __shfl_up(y, s, 64);
                if (lane >= s) y += t;
            }
            if (lane < 16) wsum[lane] = y;
        }
        __syncthreads();
        int carry = carry_s;
        int wofs = (wid == 0) ? 0 : wsum[wid - 1];
        if (i < n) off[i] = carry + wofs + x - v;
        __syncthreads();
        if (tid == 0) carry_s = carry + wsum[15];
        __syncthreads();
    }
}

// ---------------- bucketed placement: dense per-bucket appends ----------------
// gtail starts as exclusive bucket offsets; advanced to inclusive ends.
// edge packed: key = (row & 63) << 17 | col   (col < 2^17), val as int bits
__global__ __launch_bounds__(256) void k_bucket_place(const int* __restrict__ rows,
                                                      const int* __restrict__ cols,
                                                      const float* __restrict__ vals,
                                                      int* __restrict__ gtail,
                                                      int2* __restrict__ out, int nnz, int nb) {
    __shared__ int h[NBMAX];
    __shared__ int base_s[NBMAX];
    int tid = threadIdx.x;
    for (int i = tid; i < nb; i += 256) h[i] = 0;
    __syncthreads();
    int er[EPT], ec[EPT];
    float ev[EPT];
    long b0 = (long)blockIdx.x * EPB;
#pragma unroll
    for (int j = 0; j < EPT; ++j) {
        long e = b0 + j * 256 + tid;
        if (e < nnz) {
            er[j] = rows[e];
            ec[j] = cols[e];
            ev[j] = vals[e];
            atomicAdd(&h[er[j] >> 6], 1);
        } else {
            er[j] = -1;
        }
    }
    __syncthreads();
    for (int i = tid; i < nb; i += 256) {
        int v = h[i];
        if (v) base_s[i] = atomicAdd(&gtail[i], v);
        h[i] = 0; // reuse as local cursor
    }
    __syncthreads();
#pragma unroll
    for (int j = 0; j < EPT; ++j) {
        if (er[j] >= 0) {
            int bk = er[j] >> 6;
            int loc = atomicAdd(&h[bk], 1);
            out[base_s[bk] + loc] = make_int2(((er[j] & 63) << 17) | ec[j], __float_as_int(ev[j]));
        }
    }
}

// ---------------- sorted-bucket SpMM: counting-sort in LDS, register accumulation ----------------
// block = 512 threads (8 waves) per 64-row bucket; wave w owns rows [w*8, w*8+8)
__global__ __launch_bounds__(512) void k_spmm_sorted(const int* __restrict__ gtail,
                                                     const int2* __restrict__ edges,
                                                     const ushort* __restrict__ src,
                                                     ushort* __restrict__ dst,
                                                     const float* __restrict__ bias,
                                                     int nrows) {
    __shared__ int2 se[CHUNK];      // 32 KB sorted edge buffer
    __shared__ int hist[RPB], sofs[RPB], cur[RPB];
    int tid = threadIdx.x, lane = tid & 63, w = tid >> 6;
    int bk = blockIdx.x;
    int begin = bk ? gtail[bk - 1] : 0;
    int end = gtail[bk];

    float2 acc[8] = {};
    for (int cbase = begin; cbase < end; cbase += CHUNK) {
        int m = end - cbase;
        if (m > CHUNK) m = CHUNK;
        if (tid < RPB) hist[tid] = 0;
        __syncthreads();
        // stage into regs + histogram local rows
        int2 er[CHUNK / 512];
#pragma unroll
        for (int j = 0; j < CHUNK / 512; ++j) {
            int idx = j * 512 + tid;
            if (idx < m) {
                er[j] = edges[cbase + idx];
                atomicAdd(&hist[er[j].x >> 17], 1);
            } else {
                er[j].x = -1;
            }
        }
        __syncthreads();
        // exclusive scan of 64 counts by wave 0
        if (w == 0) {
            int v = hist[lane];
            int x = v;
#pragma unroll
            for (int s = 1; s < 64; s <<= 1) {
                int t = __shfl_up(x, s, 64);
                if (lane >= s) x += t;
            }
            sofs[lane] = x - v;
            cur[lane] = x - v;
        }
        __syncthreads();
        // scatter into sorted order
#pragma unroll
        for (int j = 0; j < CHUNK / 512; ++j) {
            if (er[j].x >= 0) {
                int lr = er[j].x >> 17;
                int p = atomicAdd(&cur[lr], 1);
                se[p] = er[j];
            }
        }
        __syncthreads();
        // process: wave w accumulates its 8 rows from sorted segments
#pragma unroll
        for (int i = 0; i < 8; ++i) {
            int lr = w * 8 + i;
            int e = sofs[lr];
            int s1 = e + hist[lr];
            for (; e + 2 <= s1; e += 2) {
                int2 e0 = se[e], e1 = se[e + 1];
                unsigned u0 = *(const unsigned*)(src + (long)(e0.x & 0x1FFFF) * EMB + lane * 2);
                unsigned u1 = *(const unsigned*)(src + (long)(e1.x & 0x1FFFF) * EMB + lane * 2);
                float v0 = __int_as_float(e0.y), v1 = __int_as_float(e1.y);
                acc[i].x += v0 * bflo(u0) + v1 * bflo(u1);
                acc[i].y += v0 * bfhi(u0) + v1 * bfhi(u1);
            }
            if (e < s1) {
                int2 e0 = se[e];
                unsigned u0 = *(const unsigned*)(src + (long)(e0.x & 0x1FFFF) * EMB + lane * 2);
                float v0 = __int_as_float(e0.y);
                acc[i].x += v0 * bflo(u0);
                acc[i].y += v0 * bfhi(u0);
            }
        }
        __syncthreads(); // LDS reuse across chunks
    }
    // epilogue: wave w writes rows w*8..w*8+7 (coalesced 256B per row)
#pragma unroll
    for (int i = 0; i < 8; ++i) {
        int r = bk * RPB + w * 8 + i;
        if (r < nrows) {
            float a = acc[i].x, c = acc[i].y;
            if (bias) {
                a += bias[lane * 2];
                c += bias[lane * 2 + 1];
            }
            unsigned o = (unsigned)f2bf(a) | ((unsigned)f2bf(c) << 16);
            *((unsigned*)(dst + (long)r * EMB) + lane) = o;
        }
    }
}

// ---------------- xw = xb @ Wt^T via MFMA (M=100000, N=128, K=128), bf16 out ----------------
__global__ __launch_bounds__(256) void k_xw_mfma(const ushort* __restrict__ A,
                                                 const ushort* __restrict__ Wt,
                                                 ushort* __restrict__ xw) {
    int wid = threadIdx.x >> 6;
    int lane = threadIdx.x & 63;
    int wm = wid >> 1, wn = wid & 1;
    long m0 = (long)blockIdx.x * 128 + wm * 64;
    int n0 = wn * 64;
    int r = lane & 15;
    int kg = lane >> 4;

    f32x4 acc[4][4] = {};
#pragma unroll
    for (int ks = 0; ks < 4; ++ks) {
        bf16x8 a[4], b[4];
#pragma unroll
        for (int mf = 0; mf < 4; ++mf) {
            long row = m0 + mf * 16 + r;
            if (row >= N_TOTAL) row = N_TOTAL - 1;
            a[mf] = *(const bf16x8*)(A + row * EMB + ks * 32 + kg * 8);
        }
#pragma unroll
        for (int nf = 0; nf < 4; ++nf) {
            int row = n0 + nf * 16 + r;
            b[nf] = *(const bf16x8*)(Wt + (long)row * EMB + ks * 32 + kg * 8);
        }
#pragma unroll
        for (int mf = 0; mf < 4; ++mf)
#pragma unroll
            for (int nf = 0; nf < 4; ++nf)
                acc[mf][nf] = __builtin_amdgcn_mfma_f32_16x16x32_bf16(a[mf], b[nf], acc[mf][nf], 0, 0, 0);
    }
#pragma unroll
    for (int mf = 0; mf < 4; ++mf) {
#pragma unroll
        for (int nf = 0; nf < 4; ++nf) {
            int col = n0 + nf * 16 + r;
#pragma unroll
            for (int j = 0; j < 4; ++j) {
                long row = m0 + mf * 16 + kg * 4 + j;
                if (row < N_TOTAL) xw[row * EMB + col] = f2bf(acc[mf][nf][j]);
            }
        }
    }
}

// ---------------- gather bf16 rows (256B row copy) ----------------
__global__ void k_gather_rows_bf16(const ushort* __restrict__ src, const int* __restrict__ idx,
                                   ushort* __restrict__ dst, int n) {
    int t = blockIdx.x * blockDim.x + threadIdx.x;
    int i = t >> 4;
    int d = (t & 15) << 3;
    if (i >= n) return;
    *(uint4*)(dst + (long)i * EMB + d) = *(const uint4*)(src + (long)idx[i] * EMB + d);
}

// ---------------- out[2048, 50000] = hb @ hi^T via MFMA bf16 ----------------
__global__ __launch_bounds__(256) void k_score_mfma(const ushort* __restrict__ A,
                                                    const ushort* __restrict__ B,
                                                    float* __restrict__ C) {
    int wid = threadIdx.x >> 6;
    int lane = threadIdx.x & 63;
    int wm = wid >> 1, wn = wid & 1;
    long m0 = (long)blockIdx.y * 128 + wm * 64;
    long n0 = (long)blockIdx.x * 128 + wn * 64;
    int r = lane & 15;
    int kg = lane >> 4;

    f32x4 acc[4][4] = {};
#pragma unroll
    for (int ks = 0; ks < 4; ++ks) {
        bf16x8 a[4], b[4];
#pragma unroll
        for (int mf = 0; mf < 4; ++mf) {
            long row = m0 + mf * 16 + r;
            a[mf] = *(const bf16x8*)(A + row * EMB + ks * 32 + kg * 8);
        }
#pragma unroll
        for (int nf = 0; nf < 4; ++nf) {
            long row = n0 + nf * 16 + r;
            if (row >= N_SCORE) row = N_SCORE - 1;
            b[nf] = *(const bf16x8*)(B + row * EMB + ks * 32 + kg * 8);
        }
#pragma unroll
        for (int mf = 0; mf < 4; ++mf)
#pragma unroll
            for (int nf = 0; nf < 4; ++nf)
                acc[mf][nf] = __builtin_amdgcn_mfma_f32_16x16x32_bf16(a[mf], b[nf], acc[mf][nf], 0, 0, 0);
    }
#pragma unroll
    for (int mf = 0; mf < 4; ++mf) {
#pragma unroll
        for (int nf = 0; nf < 4; ++nf) {
            long col = n0 + nf * 16 + r;
            if (col < N_SCORE) {
#pragma unroll
                for (int j = 0; j < 4; ++j) {
                    long row = m0 + mf * 16 + kg * 4 + j;
                    C[row * N_SCORE + col] = acc[mf][nf][j];
                }
            }
        }
    }
}

extern "C" void kernel_launch(void* const* d_in, const int* in_sizes, int n_in,
                              void* d_out, int out_size, void* d_ws, size_t ws_size,
                              hipStream_t stream) {
    const float* emb_table      = (const float*)d_in[0];
    const float* W              = (const float*)d_in[1];
    const float* b              = (const float*)d_in[2];
    const float* sess_vals      = (const float*)d_in[3];
    const float* A_vals         = (const float*)d_in[4];
    const int*   batch_idxes    = (const int*)d_in[5];
    const int*   item_idxes     = (const int*)d_in[6];
    const int*   item_emb_idxes = (const int*)d_in[7];
    const int*   sess_rows      = (const int*)d_in[8];
    const int*   sess_cols      = (const int*)d_in[9];
    const int*   A_rows         = (const int*)d_in[10];
    const int*   A_cols         = (const int*)d_in[11];
    float* out = (float*)d_out;

    // -------- workspace layout (bytes), ~120 MB --------
    char* base = (char*)d_ws;
    ushort* xb     = (ushort*)(base + 0);            // [N_TOTAL,128] bf16
    ushort* xw     = (ushort*)(base + 25600000L);    // [N_TOTAL,128] bf16
    ushort* h1     = (ushort*)(base + 51200000L);    // [N_TOTAL,128] bf16
    int2*   edgA   = (int2*)  (base + 76800000L);    // 3.2M x 8B bucketed
    int2*   edgS   = (int2*)  (base + 102400000L);   // 500K x 8B bucketed
    ushort* Wt     = (ushort*)(base + 106400000L);   // 128x128 bf16
    ushort* hb     = (ushort*)(base + 106432768L);   // [BATCH,128] bf16
    ushort* hi     = (ushort*)(base + 106957056L);   // [N_SCORE,128] bf16
    int*    cntBA  = (int*)   (base + 119757056L);   // NB_A
    int*    gtailA = (int*)   (base + 119763456L);   // NB_A
    int*    cntBS  = (int*)   (base + 119769856L);   // NB_S
    int*    gtailS = (int*)   (base + 119773056L);   // NB_S

    ushort* xb_item = xb + (long)N_SESS * EMB;

    // ---- session: bucket build ----
    hipMemsetAsync(cntBS, 0, NB_S * sizeof(int), stream);
    k_bucket_hist<<<(NNZ_S + EPB - 1) / EPB, 256, 0, stream>>>(sess_rows, cntBS, NNZ_S, NB_S);
    k_scan_excl<<<1, 1024, 0, stream>>>(cntBS, gtailS, NB_S);
    k_bucket_place<<<(NNZ_S + EPB - 1) / EPB, 256, 0, stream>>>(sess_rows, sess_cols, sess_vals,
                                                                gtailS, edgS, NNZ_S, NB_S);
    // ---- gather item embeddings (bf16) + W transpose ----
    k_gather_items_bf16<<<(N_ITEMS * 32 + 255) / 256, 256, 0, stream>>>(emb_table, item_emb_idxes, xb_item);
    k_convW<<<64, 256, 0, stream>>>(W, Wt);
    // ---- spmm1: session rows of xb ----
    k_spmm_sorted<<<NB_S, 512, 0, stream>>>(gtailS, edgS, xb_item, xb, nullptr, N_SESS);
    // ---- xw = xb @ W (MFMA) ----
    k_xw_mfma<<<(N_TOTAL + 127) / 128, 256, 0, stream>>>(xb, Wt, xw);
    // ---- A: bucket build ----
    hipMemsetAsync(cntBA, 0, NB_A * sizeof(int), stream);
    k_bucket_hist<<<(NNZ_A + EPB - 1) / EPB, 256, 0, stream>>>(A_rows, cntBA, NNZ_A, NB_A);
    k_scan_excl<<<1, 1024, 0, stream>>>(cntBA, gtailA, NB_A);
    k_bucket_place<<<(NNZ_A + EPB - 1) / EPB, 256, 0, stream>>>(A_rows, A_cols, A_vals,
                                                                gtailA, edgA, NNZ_A, NB_A);
    // ---- spmm2 + fused bias -> h1 (bf16) ----
    k_spmm_sorted<<<NB_A, 512, 0, stream>>>(gtailA, edgA, xw, h1, b, N_TOTAL);
    // ---- gather hb, hi ----
    k_gather_rows_bf16<<<(BATCH * 16 + 255) / 256, 256, 0, stream>>>(h1, batch_idxes, hb, BATCH);
    k_gather_rows_bf16<<<(N_SCORE * 16 + 255) / 256, 256, 0, stream>>>(h1, item_idxes, hi, N_SCORE);
    // ---- score ----
    dim3 grid((N_SCORE + 127) / 128, BATCH / 128);
    k_score_mfma<<<grid, 256, 0, stream>>>(hb, hi, out);
}

// Round 7
// 489.158 us; speedup vs baseline: 6.3864x; 1.1855x over previous
//
#include <hip/hip_runtime.h>

#define EMB 128
#define N_ITEMS 50000
#define N_SESS 50000
#define N_TOTAL 100000
#define NNZ_S 500000
#define NNZ_A 3200000
#define BATCH 2048
#define N_SCORE 50000

#define RPB 64                                 // rows per bucket
#define NB_A ((N_TOTAL + RPB - 1) / RPB)       // 1563
#define NB_S ((N_SESS + RPB - 1) / RPB)        // 782
#define NBMAX 1600
#define EPT 8
#define EPB (256 * EPT)                        // 2048 edges per block (build kernels)
#define CHUNK 4096                             // edges staged per sort pass

typedef __attribute__((ext_vector_type(8))) short bf16x8;
typedef __attribute__((ext_vector_type(4))) float f32x4;

__device__ inline ushort f2bf(float f) {
    unsigned u = __float_as_uint(f);
    unsigned r = (u + 0x7fff + ((u >> 16) & 1)) >> 16;
    return (ushort)r;
}
__device__ inline float bflo(unsigned u) { return __uint_as_float(u << 16); }
__device__ inline float bfhi(unsigned u) { return __uint_as_float(u & 0xffff0000u); }

// ---------------- mark needed h1 rows ----------------
__global__ void k_mark(const int* __restrict__ idx, int n, unsigned* __restrict__ bm) {
    int i = blockIdx.x * 256 + threadIdx.x;
    if (i < n) {
        int r = idx[i];
        atomicOr(&bm[r >> 5], 1u << (r & 31));
    }
}

// ---------------- gather x_item = bf16(emb_table[item_emb_idxes]) ----------------
__global__ void k_gather_items_bf16(const float* __restrict__ emb, const int* __restrict__ idx,
                                    ushort* __restrict__ xb_item) {
    int t = blockIdx.x * blockDim.x + threadIdx.x;
    int i = t >> 5;
    int d = (t & 31) << 2;
    if (i >= N_ITEMS) return;
    float4 v = *(const float4*)(emb + (long)idx[i] * EMB + d);
    uint2 o;
    o.x = (unsigned)f2bf(v.x) | ((unsigned)f2bf(v.y) << 16);
    o.y = (unsigned)f2bf(v.z) | ((unsigned)f2bf(v.w) << 16);
    *(uint2*)(xb_item + (long)i * EMB + d) = o;
}

// ---------------- W -> Wt bf16 (transposed: Wt[n][k] = W[k][n]) ----------------
__global__ void k_convW(const float* __restrict__ W, ushort* __restrict__ Wt) {
    int i = blockIdx.x * 256 + threadIdx.x;
    if (i >= 128 * 128) return;
    int n = i >> 7, k = i & 127;
    Wt[n * 128 + k] = f2bf(W[k * 128 + n]);
}

// ---------------- bucket histogram (optionally row-filtered) ----------------
__global__ __launch_bounds__(256) void k_bucket_hist(const int* __restrict__ rows,
                                                     int* __restrict__ cnt, int nnz, int nb,
                                                     const unsigned* __restrict__ bm) {
    __shared__ int h[NBMAX];
    int tid = threadIdx.x;
    for (int i = tid; i < nb; i += 256) h[i] = 0;
    __syncthreads();
    long b0 = (long)blockIdx.x * EPB;
#pragma unroll
    for (int j = 0; j < EPT; ++j) {
        long e = b0 + j * 256 + tid;
        if (e < nnz) {
            int r = rows[e];
            if (!bm || ((bm[r >> 5] >> (r & 31)) & 1))
                atomicAdd(&h[r >> 6], 1);
        }
    }
    __syncthreads();
    for (int i = tid; i < nb; i += 256) {
        int v = h[i];
        if (v) atomicAdd(&cnt[i], v);
    }
}

// ---------------- single-block exclusive scan with carry ----------------
__global__ __launch_bounds__(1024) void k_scan_excl(const int* __restrict__ cnt,
                                                    int* __restrict__ off, int n) {
    __shared__ int wsum[16];
    __shared__ int carry_s;
    int tid = threadIdx.x, lane = tid & 63, wid = tid >> 6;
    if (tid == 0) carry_s = 0;
    __syncthreads();
    for (int base = 0; base < n; base += 1024) {
        int i = base + tid;
        int v = (i < n) ? cnt[i] : 0;
        int x = v;
#pragma unroll
        for (int s = 1; s < 64; s <<= 1) {
            int t = __shfl_up(x, s, 64);
            if (lane >= s) x += t;
        }
        if (lane == 63) wsum[wid] = x;
        __syncthreads();
        if (wid == 0) {
            int y = (lane < 16) ? wsum[lane] : 0;
#pragma unroll
            for (int s = 1; s < 16; s <<= 1) {
                int t = __shfl_up(y, s, 64);
                if (lane >= s) y += t;
            }
            if (lane < 16) wsum[lane] = y;
        }
        __syncthreads();
        int carry = carry_s;
        int wofs = (wid == 0) ? 0 : wsum[wid - 1];
        if (i < n) off[i] = carry + wofs + x - v;
        __syncthreads();
        if (tid == 0) carry_s = carry + wsum[15];
        __syncthreads();
    }
}

// ---------------- bucketed placement (optionally row-filtered) ----------------
// edge packed: key = (row & 63) << 17 | col   (col < 2^17), val as int bits
__global__ __launch_bounds__(256) void k_bucket_place(const int* __restrict__ rows,
                                                      const int* __restrict__ cols,
                                                      const float* __restrict__ vals,
                                                      int* __restrict__ gtail,
                                                      int2* __restrict__ out, int nnz, int nb,
                                                      const unsigned* __restrict__ bm) {
    __shared__ int h[NBMAX];
    __shared__ int base_s[NBMAX];
    int tid = threadIdx.x;
    for (int i = tid; i < nb; i += 256) h[i] = 0;
    __syncthreads();
    int er[EPT], ec[EPT];
    float ev[EPT];
    long b0 = (long)blockIdx.x * EPB;
#pragma unroll
    for (int j = 0; j < EPT; ++j) {
        long e = b0 + j * 256 + tid;
        er[j] = -1;
        if (e < nnz) {
            int r = rows[e];
            if (!bm || ((bm[r >> 5] >> (r & 31)) & 1)) {
                er[j] = r;
                ec[j] = cols[e];
                ev[j] = vals[e];
                atomicAdd(&h[r >> 6], 1);
            }
        }
    }
    __syncthreads();
    for (int i = tid; i < nb; i += 256) {
        int v = h[i];
        if (v) base_s[i] = atomicAdd(&gtail[i], v);
        h[i] = 0; // reuse as local cursor
    }
    __syncthreads();
#pragma unroll
    for (int j = 0; j < EPT; ++j) {
        if (er[j] >= 0) {
            int bk = er[j] >> 6;
            int loc = atomicAdd(&h[bk], 1);
            out[base_s[bk] + loc] = make_int2(((er[j] & 63) << 17) | ec[j], __float_as_int(ev[j]));
        }
    }
}

// ---------------- sorted-bucket SpMM: counting-sort in LDS, register accumulation ----------------
__global__ __launch_bounds__(512) void k_spmm_sorted(const int* __restrict__ gtail,
                                                     const int2* __restrict__ edges,
                                                     const ushort* __restrict__ src,
                                                     ushort* __restrict__ dst,
                                                     const float* __restrict__ bias,
                                                     int nrows) {
    __shared__ int2 se[CHUNK];      // 32 KB sorted edge buffer
    __shared__ int hist[RPB], sofs[RPB], cur[RPB];
    int tid = threadIdx.x, lane = tid & 63, w = tid >> 6;
    int bk = blockIdx.x;
    int begin = bk ? gtail[bk - 1] : 0;
    int end = gtail[bk];

    float2 acc[8] = {};
    for (int cbase = begin; cbase < end; cbase += CHUNK) {
        int m = end - cbase;
        if (m > CHUNK) m = CHUNK;
        if (tid < RPB) hist[tid] = 0;
        __syncthreads();
        int2 er[CHUNK / 512];
#pragma unroll
        for (int j = 0; j < CHUNK / 512; ++j) {
            int idx = j * 512 + tid;
            if (idx < m) {
                er[j] = edges[cbase + idx];
                atomicAdd(&hist[er[j].x >> 17], 1);
            } else {
                er[j].x = -1;
            }
        }
        __syncthreads();
        if (w == 0) {
            int v = hist[lane];
            int x = v;
#pragma unroll
            for (int s = 1; s < 64; s <<= 1) {
                int t = __shfl_up(x, s, 64);
                if (lane >= s) x += t;
            }
            sofs[lane] = x - v;
            cur[lane] = x - v;
        }
        __syncthreads();
#pragma unroll
        for (int j = 0; j < CHUNK / 512; ++j) {
            if (er[j].x >= 0) {
                int lr = er[j].x >> 17;
                int p = atomicAdd(&cur[lr], 1);
                se[p] = er[j];
            }
        }
        __syncthreads();
#pragma unroll
        for (int i = 0; i < 8; ++i) {
            int lr = w * 8 + i;
            int e = sofs[lr];
            int s1 = e + hist[lr];
            for (; e + 2 <= s1; e += 2) {
                int2 e0 = se[e], e1 = se[e + 1];
                unsigned u0 = *(const unsigned*)(src + (long)(e0.x & 0x1FFFF) * EMB + lane * 2);
                unsigned u1 = *(const unsigned*)(src + (long)(e1.x & 0x1FFFF) * EMB + lane * 2);
                float v0 = __int_as_float(e0.y), v1 = __int_as_float(e1.y);
                acc[i].x += v0 * bflo(u0) + v1 * bflo(u1);
                acc[i].y += v0 * bfhi(u0) + v1 * bfhi(u1);
            }
            if (e < s1) {
                int2 e0 = se[e];
                unsigned u0 = *(const unsigned*)(src + (long)(e0.x & 0x1FFFF) * EMB + lane * 2);
                float v0 = __int_as_float(e0.y);
                acc[i].x += v0 * bflo(u0);
                acc[i].y += v0 * bfhi(u0);
            }
        }
        __syncthreads();
    }
#pragma unroll
    for (int i = 0; i < 8; ++i) {
        int r = bk * RPB + w * 8 + i;
        if (r < nrows) {
            float a = acc[i].x, c = acc[i].y;
            if (bias) {
                a += bias[lane * 2];
                c += bias[lane * 2 + 1];
            }
            unsigned o = (unsigned)f2bf(a) | ((unsigned)f2bf(c) << 16);
            *((unsigned*)(dst + (long)r * EMB) + lane) = o;
        }
    }
}

// ---------------- dst = A @ Wt^T via MFMA (M=nrows, N=128, K=128), bf16 out ----------------
__global__ __launch_bounds__(256) void k_xw_mfma(const ushort* __restrict__ A,
                                                 const ushort* __restrict__ Wt,
                                                 ushort* __restrict__ xw, int nrows) {
    int wid = threadIdx.x >> 6;
    int lane = threadIdx.x & 63;
    int wm = wid >> 1, wn = wid & 1;
    long m0 = (long)blockIdx.x * 128 + wm * 64;
    int n0 = wn * 64;
    int r = lane & 15;
    int kg = lane >> 4;

    f32x4 acc[4][4] = {};
#pragma unroll
    for (int ks = 0; ks < 4; ++ks) {
        bf16x8 a[4], b[4];
#pragma unroll
        for (int mf = 0; mf < 4; ++mf) {
            long row = m0 + mf * 16 + r;
            if (row >= nrows) row = nrows - 1;
            a[mf] = *(const bf16x8*)(A + row * EMB + ks * 32 + kg * 8);
        }
#pragma unroll
        for (int nf = 0; nf < 4; ++nf) {
            int row = n0 + nf * 16 + r;
            b[nf] = *(const bf16x8*)(Wt + (long)row * EMB + ks * 32 + kg * 8);
        }
#pragma unroll
        for (int mf = 0; mf < 4; ++mf)
#pragma unroll
            for (int nf = 0; nf < 4; ++nf)
                acc[mf][nf] = __builtin_amdgcn_mfma_f32_16x16x32_bf16(a[mf], b[nf], acc[mf][nf], 0, 0, 0);
    }
#pragma unroll
    for (int mf = 0; mf < 4; ++mf) {
#pragma unroll
        for (int nf = 0; nf < 4; ++nf) {
            int col = n0 + nf * 16 + r;
#pragma unroll
            for (int j = 0; j < 4; ++j) {
                long row = m0 + mf * 16 + kg * 4 + j;
                if (row < nrows) xw[row * EMB + col] = f2bf(acc[mf][nf][j]);
            }
        }
    }
}

// ---------------- gather bf16 rows (256B row copy) ----------------
__global__ void k_gather_rows_bf16(const ushort* __restrict__ src, const int* __restrict__ idx,
                                   ushort* __restrict__ dst, int n) {
    int t = blockIdx.x * blockDim.x + threadIdx.x;
    int i = t >> 4;
    int d = (t & 15) << 3;
    if (i >= n) return;
    *(uint4*)(dst + (long)i * EMB + d) = *(const uint4*)(src + (long)idx[i] * EMB + d);
}

// ---------------- out[2048, 50000] = hb @ hi^T via MFMA bf16 ----------------
__global__ __launch_bounds__(256) void k_score_mfma(const ushort* __restrict__ A,
                                                    const ushort* __restrict__ B,
                                                    float* __restrict__ C) {
    int wid = threadIdx.x >> 6;
    int lane = threadIdx.x & 63;
    int wm = wid >> 1, wn = wid & 1;
    long m0 = (long)blockIdx.y * 128 + wm * 64;
    long n0 = (long)blockIdx.x * 128 + wn * 64;
    int r = lane & 15;
    int kg = lane >> 4;

    f32x4 acc[4][4] = {};
#pragma unroll
    for (int ks = 0; ks < 4; ++ks) {
        bf16x8 a[4], b[4];
#pragma unroll
        for (int mf = 0; mf < 4; ++mf) {
            long row = m0 + mf * 16 + r;
            a[mf] = *(const bf16x8*)(A + row * EMB + ks * 32 + kg * 8);
        }
#pragma unroll
        for (int nf = 0; nf < 4; ++nf) {
            long row = n0 + nf * 16 + r;
            if (row >= N_SCORE) row = N_SCORE - 1;
            b[nf] = *(const bf16x8*)(B + row * EMB + ks * 32 + kg * 8);
        }
#pragma unroll
        for (int mf = 0; mf < 4; ++mf)
#pragma unroll
            for (int nf = 0; nf < 4; ++nf)
                acc[mf][nf] = __builtin_amdgcn_mfma_f32_16x16x32_bf16(a[mf], b[nf], acc[mf][nf], 0, 0, 0);
    }
#pragma unroll
    for (int mf = 0; mf < 4; ++mf) {
#pragma unroll
        for (int nf = 0; nf < 4; ++nf) {
            long col = n0 + nf * 16 + r;
            if (col < N_SCORE) {
#pragma unroll
                for (int j = 0; j < 4; ++j) {
                    long row = m0 + mf * 16 + kg * 4 + j;
                    __builtin_nontemporal_store(acc[mf][nf][j], &C[row * N_SCORE + col]);
                }
            }
        }
    }
}

extern "C" void kernel_launch(void* const* d_in, const int* in_sizes, int n_in,
                              void* d_out, int out_size, void* d_ws, size_t ws_size,
                              hipStream_t stream) {
    const float* emb_table      = (const float*)d_in[0];
    const float* W              = (const float*)d_in[1];
    const float* b              = (const float*)d_in[2];
    const float* sess_vals      = (const float*)d_in[3];
    const float* A_vals         = (const float*)d_in[4];
    const int*   batch_idxes    = (const int*)d_in[5];
    const int*   item_idxes    = (const int*)d_in[6];
    const int*   item_emb_idxes = (const int*)d_in[7];
    const int*   sess_rows      = (const int*)d_in[8];
    const int*   sess_cols      = (const int*)d_in[9];
    const int*   A_rows         = (const int*)d_in[10];
    const int*   A_cols         = (const int*)d_in[11];
    float* out = (float*)d_out;

    // -------- workspace layout (bytes), ~107 MB --------
    char* base = (char*)d_ws;
    ushort*   xb_item = (ushort*)(base + 0);            // [N_ITEMS,128] bf16, 12.8MB
    ushort*   xw      = (ushort*)(base + 12800000L);    // [N_TOTAL,128] bf16, 25.6MB
    ushort*   h1      = (ushort*)(base + 38400000L);    // [N_TOTAL,128] bf16, 25.6MB
    int2*     edgA    = (int2*)  (base + 64000000L);    // up to 3.2M x 8B
    int2*     edgS    = (int2*)  (base + 89600000L);    // 500K x 8B
    ushort*   Wt      = (ushort*)(base + 93600000L);    // 128x128 bf16
    ushort*   hb      = (ushort*)(base + 93632768L);    // [BATCH,128] bf16
    ushort*   hi      = (ushort*)(base + 94157056L);    // [N_SCORE,128] bf16
    int*      cntBA   = (int*)   (base + 106957056L);   // NB_A
    int*      gtailA  = (int*)   (base + 106963456L);   // NB_A
    int*      cntBS   = (int*)   (base + 106969856L);   // NB_S
    int*      gtailS  = (int*)   (base + 106973056L);   // NB_S
    unsigned* bm      = (unsigned*)(base + 106976256L); // 3125 words

    ushort* xw_item = xw + (long)N_SESS * EMB;  // item half of xw

    // ---- needed-row bitmap for h1 ----
    hipMemsetAsync(bm, 0, 3136 * sizeof(unsigned), stream);
    k_mark<<<(BATCH + 255) / 256, 256, 0, stream>>>(batch_idxes, BATCH, bm);
    k_mark<<<(N_SCORE + 255) / 256, 256, 0, stream>>>(item_idxes, N_SCORE, bm);

    // ---- session: bucket build (unfiltered) ----
    hipMemsetAsync(cntBS, 0, NB_S * sizeof(int), stream);
    k_bucket_hist<<<(NNZ_S + EPB - 1) / EPB, 256, 0, stream>>>(sess_rows, cntBS, NNZ_S, NB_S, nullptr);
    k_scan_excl<<<1, 1024, 0, stream>>>(cntBS, gtailS, NB_S);
    k_bucket_place<<<(NNZ_S + EPB - 1) / EPB, 256, 0, stream>>>(sess_rows, sess_cols, sess_vals,
                                                                gtailS, edgS, NNZ_S, NB_S, nullptr);
    // ---- gather item embeddings (bf16) + W transpose ----
    k_gather_items_bf16<<<(N_ITEMS * 32 + 255) / 256, 256, 0, stream>>>(emb_table, item_emb_idxes, xb_item);
    k_convW<<<64, 256, 0, stream>>>(W, Wt);
    // ---- xw_item = x_item @ W (MFMA, M=50K) ----
    k_xw_mfma<<<(N_ITEMS + 127) / 128, 256, 0, stream>>>(xb_item, Wt, xw_item, N_ITEMS);
    // ---- spmm1 (reordered): xw[0:N_SESS] = S @ xw_item ----
    k_spmm_sorted<<<NB_S, 512, 0, stream>>>(gtailS, edgS, xw_item, xw, nullptr, N_SESS);
    // ---- A: bucket build, filtered to needed h1 rows ----
    hipMemsetAsync(cntBA, 0, NB_A * sizeof(int), stream);
    k_bucket_hist<<<(NNZ_A + EPB - 1) / EPB, 256, 0, stream>>>(A_rows, cntBA, NNZ_A, NB_A, bm);
    k_scan_excl<<<1, 1024, 0, stream>>>(cntBA, gtailA, NB_A);
    k_bucket_place<<<(NNZ_A + EPB - 1) / EPB, 256, 0, stream>>>(A_rows, A_cols, A_vals,
                                                                gtailA, edgA, NNZ_A, NB_A, bm);
    // ---- spmm2 + fused bias -> h1 (needed rows valid) ----
    k_spmm_sorted<<<NB_A, 512, 0, stream>>>(gtailA, edgA, xw, h1, b, N_TOTAL);
    // ---- gather hb, hi ----
    k_gather_rows_bf16<<<(BATCH * 16 + 255) / 256, 256, 0, stream>>>(h1, batch_idxes, hb, BATCH);
    k_gather_rows_bf16<<<(N_SCORE * 16 + 255) / 256, 256, 0, stream>>>(h1, item_idxes, hi, N_SCORE);
    // ---- score ----
    dim3 grid((N_SCORE + 127) / 128, BATCH / 128);
    k_score_mfma<<<grid, 256, 0, stream>>>(hb, hi, out);
}

// Round 8
// 441.752 us; speedup vs baseline: 7.0717x; 1.1073x over previous
//
#include <hip/hip_runtime.h>

#define EMB 128
#define N_ITEMS 50000
#define N_SESS 50000
#define N_TOTAL 100000
#define NNZ_S 500000
#define NNZ_A 3200000
#define BATCH 2048
#define N_SCORE 50000

#define RPB 64                                 // rows per bucket
#define NB_A ((N_TOTAL + RPB - 1) / RPB)       // 1563
#define NB_S ((N_SESS + RPB - 1) / RPB)        // 782
#define NBMAX 1600
#define EPT 8
#define EPB (256 * EPT)                        // 2048 edges per block (build kernels)
#define NBLK_S ((NNZ_S + EPB - 1) / EPB)       // 245
#define NBLK_A ((NNZ_A + EPB - 1) / EPB)       // 1563
#define CHUNK 4096                             // edges staged per sort pass

#define SB_X ((N_SCORE + 127) / 128)           // 391
#define SB_Y (BATCH / 128)                     // 16
#define SB_TOT (SB_X * SB_Y)                   // 6256 = 8 * 782

typedef __attribute__((ext_vector_type(8))) short bf16x8;
typedef __attribute__((ext_vector_type(4))) float f32x4;

__device__ inline ushort f2bf(float f) {
    unsigned u = __float_as_uint(f);
    unsigned r = (u + 0x7fff + ((u >> 16) & 1)) >> 16;
    return (ushort)r;
}
__device__ inline float bflo(unsigned u) { return __uint_as_float(u << 16); }
__device__ inline float bfhi(unsigned u) { return __uint_as_float(u & 0xffff0000u); }

// ---------------- mark needed h1 rows (both index arrays in one launch) ----------------
__global__ void k_mark2(const int* __restrict__ a, int na, const int* __restrict__ b, int nb_,
                        unsigned* __restrict__ bm) {
    int i = blockIdx.x * 256 + threadIdx.x;
    int r = -1;
    if (i < na) r = a[i];
    else if (i < na + nb_) r = b[i - na];
    if (r >= 0) atomicOr(&bm[r >> 5], 1u << (r & 31));
}

// ---------------- gather x_item = bf16(emb[idx]) + W transpose (fused) ----------------
__global__ void k_gather_items_convW(const float* __restrict__ emb, const int* __restrict__ idx,
                                     ushort* __restrict__ xb_item,
                                     const float* __restrict__ W, ushort* __restrict__ Wt) {
    int blk = blockIdx.x;
    int tid = threadIdx.x;
    if (blk >= (N_ITEMS * 32) / 256) { // 64 trailing blocks: W transpose
        int i = (blk - (N_ITEMS * 32) / 256) * 256 + tid;
        if (i < 128 * 128) {
            int n = i >> 7, k = i & 127;
            Wt[n * 128 + k] = f2bf(W[k * 128 + n]);
        }
        return;
    }
    int t = blk * 256 + tid;
    int i = t >> 5;
    int d = (t & 31) << 2;
    float4 v = *(const float4*)(emb + (long)idx[i] * EMB + d);
    uint2 o;
    o.x = (unsigned)f2bf(v.x) | ((unsigned)f2bf(v.y) << 16);
    o.y = (unsigned)f2bf(v.z) | ((unsigned)f2bf(v.w) << 16);
    *(uint2*)(xb_item + (long)i * EMB + d) = o;
}

// ---------------- fused bucket histogram: S blocks then A blocks (A row-filtered) ----------------
__global__ __launch_bounds__(256) void k_hist2(const int* __restrict__ sRows, int* __restrict__ cntS,
                                               const int* __restrict__ aRows, int* __restrict__ cntA,
                                               const unsigned* __restrict__ bm) {
    __shared__ int h[NBMAX];
    int tid = threadIdx.x;
    const int* rows;
    int* cnt;
    const unsigned* filt;
    int nnz, nb;
    long b0;
    if (blockIdx.x < NBLK_S) {
        rows = sRows; cnt = cntS; filt = nullptr; nnz = NNZ_S; nb = NB_S;
        b0 = (long)blockIdx.x * EPB;
    } else {
        rows = aRows; cnt = cntA; filt = bm; nnz = NNZ_A; nb = NB_A;
        b0 = (long)(blockIdx.x - NBLK_S) * EPB;
    }
    for (int i = tid; i < nb; i += 256) h[i] = 0;
    __syncthreads();
#pragma unroll
    for (int j = 0; j < EPT; ++j) {
        long e = b0 + j * 256 + tid;
        if (e < nnz) {
            int r = rows[e];
            if (!filt || ((filt[r >> 5] >> (r & 31)) & 1))
                atomicAdd(&h[r >> 6], 1);
        }
    }
    __syncthreads();
    for (int i = tid; i < nb; i += 256) {
        int v = h[i];
        if (v) atomicAdd(&cnt[i], v);
    }
}

// ---------------- fused scan: block 0 -> S, block 1 -> A ----------------
__global__ __launch_bounds__(1024) void k_scan2(const int* __restrict__ cntS, int* __restrict__ offS,
                                                const int* __restrict__ cntA, int* __restrict__ offA) {
    __shared__ int wsum[16];
    __shared__ int carry_s;
    const int* cnt = blockIdx.x ? cntA : cntS;
    int* off = blockIdx.x ? offA : offS;
    int n = blockIdx.x ? NB_A : NB_S;
    int tid = threadIdx.x, lane = tid & 63, wid = tid >> 6;
    if (tid == 0) carry_s = 0;
    __syncthreads();
    for (int base = 0; base < n; base += 1024) {
        int i = base + tid;
        int v = (i < n) ? cnt[i] : 0;
        int x = v;
#pragma unroll
        for (int s = 1; s < 64; s <<= 1) {
            int t = __shfl_up(x, s, 64);
            if (lane >= s) x += t;
        }
        if (lane == 63) wsum[wid] = x;
        __syncthreads();
        if (wid == 0) {
            int y = (lane < 16) ? wsum[lane] : 0;
#pragma unroll
            for (int s = 1; s < 16; s <<= 1) {
                int t = __shfl_up(y, s, 64);
                if (lane >= s) y += t;
            }
            if (lane < 16) wsum[lane] = y;
        }
        __syncthreads();
        int carry = carry_s;
        int wofs = (wid == 0) ? 0 : wsum[wid - 1];
        if (i < n) off[i] = carry + wofs + x - v;
        __syncthreads();
        if (tid == 0) carry_s = carry + wsum[15];
        __syncthreads();
    }
}

// ---------------- fused bucketed placement ----------------
// edge packed: key = (row & 63) << 17 | col, val as int bits
__global__ __launch_bounds__(256) void k_place2(const int* __restrict__ sRows, const int* __restrict__ sCols,
                                                const float* __restrict__ sVals, int* __restrict__ gtailS,
                                                int2* __restrict__ edgS,
                                                const int* __restrict__ aRows, const int* __restrict__ aCols,
                                                const float* __restrict__ aVals, int* __restrict__ gtailA,
                                                int2* __restrict__ edgA,
                                                const unsigned* __restrict__ bm) {
    __shared__ int h[NBMAX];
    __shared__ int base_s[NBMAX];
    int tid = threadIdx.x;
    const int *rows, *cols;
    const float* vals;
    int* gtail;
    int2* out;
    const unsigned* filt;
    int nnz, nb;
    long b0;
    if (blockIdx.x < NBLK_S) {
        rows = sRows; cols = sCols; vals = sVals; gtail = gtailS; out = edgS;
        filt = nullptr; nnz = NNZ_S; nb = NB_S;
        b0 = (long)blockIdx.x * EPB;
    } else {
        rows = aRows; cols = aCols; vals = aVals; gtail = gtailA; out = edgA;
        filt = bm; nnz = NNZ_A; nb = NB_A;
        b0 = (long)(blockIdx.x - NBLK_S) * EPB;
    }
    for (int i = tid; i < nb; i += 256) h[i] = 0;
    __syncthreads();
    int er[EPT], ec[EPT];
    float ev[EPT];
#pragma unroll
    for (int j = 0; j < EPT; ++j) {
        long e = b0 + j * 256 + tid;
        er[j] = -1;
        if (e < nnz) {
            int r = rows[e];
            if (!filt || ((filt[r >> 5] >> (r & 31)) & 1)) {
                er[j] = r;
                ec[j] = cols[e];
                ev[j] = vals[e];
                atomicAdd(&h[r >> 6], 1);
            }
        }
    }
    __syncthreads();
    for (int i = tid; i < nb; i += 256) {
        int v = h[i];
        if (v) base_s[i] = atomicAdd(&gtail[i], v);
        h[i] = 0; // reuse as local cursor
    }
    __syncthreads();
#pragma unroll
    for (int j = 0; j < EPT; ++j) {
        if (er[j] >= 0) {
            int bk = er[j] >> 6;
            int loc = atomicAdd(&h[bk], 1);
            out[base_s[bk] + loc] = make_int2(((er[j] & 63) << 17) | ec[j], __float_as_int(ev[j]));
        }
    }
}

// ---------------- sorted-bucket SpMM: counting-sort in LDS, register accumulation ----------------
__global__ __launch_bounds__(512) void k_spmm_sorted(const int* __restrict__ gtail,
                                                     const int2* __restrict__ edges,
                                                     const ushort* __restrict__ src,
                                                     ushort* __restrict__ dst,
                                                     const float* __restrict__ bias,
                                                     int nrows,
                                                     const unsigned* __restrict__ bm) {
    __shared__ int2 se[CHUNK];      // 32 KB sorted edge buffer
    __shared__ int hist[RPB], sofs[RPB], cur[RPB];
    int tid = threadIdx.x, lane = tid & 63, w = tid >> 6;
    int bk = blockIdx.x;
    int begin = bk ? gtail[bk - 1] : 0;
    int end = gtail[bk];

    float2 acc[8] = {};
    for (int cbase = begin; cbase < end; cbase += CHUNK) {
        int m = end - cbase;
        if (m > CHUNK) m = CHUNK;
        if (tid < RPB) hist[tid] = 0;
        __syncthreads();
        int2 er[CHUNK / 512];
#pragma unroll
        for (int j = 0; j < CHUNK / 512; ++j) {
            int idx = j * 512 + tid;
            if (idx < m) {
                er[j] = edges[cbase + idx];
                atomicAdd(&hist[er[j].x >> 17], 1);
            } else {
                er[j].x = -1;
            }
        }
        __syncthreads();
        if (w == 0) {
            int v = hist[lane];
            int x = v;
#pragma unroll
            for (int s = 1; s < 64; s <<= 1) {
                int t = __shfl_up(x, s, 64);
                if (lane >= s) x += t;
            }
            sofs[lane] = x - v;
            cur[lane] = x - v;
        }
        __syncthreads();
#pragma unroll
        for (int j = 0; j < CHUNK / 512; ++j) {
            if (er[j].x >= 0) {
                int lr = er[j].x >> 17;
                int p = atomicAdd(&cur[lr], 1);
                se[p] = er[j];
            }
        }
        __syncthreads();
#pragma unroll
        for (int i = 0; i < 8; ++i) {
            int lr = w * 8 + i;
            int e = sofs[lr];
            int s1 = e + hist[lr];
            for (; e + 4 <= s1; e += 4) {
                int2 e0 = se[e], e1 = se[e + 1], e2 = se[e + 2], e3 = se[e + 3];
                unsigned u0 = *(const unsigned*)(src + (long)(e0.x & 0x1FFFF) * EMB + lane * 2);
                unsigned u1 = *(const unsigned*)(src + (long)(e1.x & 0x1FFFF) * EMB + lane * 2);
                unsigned u2 = *(const unsigned*)(src + (long)(e2.x & 0x1FFFF) * EMB + lane * 2);
                unsigned u3 = *(const unsigned*)(src + (long)(e3.x & 0x1FFFF) * EMB + lane * 2);
                float v0 = __int_as_float(e0.y), v1 = __int_as_float(e1.y);
                float v2 = __int_as_float(e2.y), v3 = __int_as_float(e3.y);
                acc[i].x += v0 * bflo(u0) + v1 * bflo(u1) + v2 * bflo(u2) + v3 * bflo(u3);
                acc[i].y += v0 * bfhi(u0) + v1 * bfhi(u1) + v2 * bfhi(u2) + v3 * bfhi(u3);
            }
            for (; e < s1; ++e) {
                int2 e0 = se[e];
                unsigned u0 = *(const unsigned*)(src + (long)(e0.x & 0x1FFFF) * EMB + lane * 2);
                float v0 = __int_as_float(e0.y);
                acc[i].x += v0 * bflo(u0);
                acc[i].y += v0 * bfhi(u0);
            }
        }
        __syncthreads();
    }
#pragma unroll
    for (int i = 0; i < 8; ++i) {
        int r = bk * RPB + w * 8 + i;
        if (r < nrows && (!bm || ((bm[r >> 5] >> (r & 31)) & 1))) {
            float a = acc[i].x, c = acc[i].y;
            if (bias) {
                a += bias[lane * 2];
                c += bias[lane * 2 + 1];
            }
            unsigned o = (unsigned)f2bf(a) | ((unsigned)f2bf(c) << 16);
            *((unsigned*)(dst + (long)r * EMB) + lane) = o;
        }
    }
}

// ---------------- dst = A @ Wt^T via MFMA (M=nrows, N=128, K=128), bf16 out ----------------
__global__ __launch_bounds__(256) void k_xw_mfma(const ushort* __restrict__ A,
                                                 const ushort* __restrict__ Wt,
                                                 ushort* __restrict__ xw, int nrows) {
    int wid = threadIdx.x >> 6;
    int lane = threadIdx.x & 63;
    int wm = wid >> 1, wn = wid & 1;
    long m0 = (long)blockIdx.x * 128 + wm * 64;
    int n0 = wn * 64;
    int r = lane & 15;
    int kg = lane >> 4;

    f32x4 acc[4][4] = {};
#pragma unroll
    for (int ks = 0; ks < 4; ++ks) {
        bf16x8 a[4], b[4];
#pragma unroll
        for (int mf = 0; mf < 4; ++mf) {
            long row = m0 + mf * 16 + r;
            if (row >= nrows) row = nrows - 1;
            a[mf] = *(const bf16x8*)(A + row * EMB + ks * 32 + kg * 8);
        }
#pragma unroll
        for (int nf = 0; nf < 4; ++nf) {
            int row = n0 + nf * 16 + r;
            b[nf] = *(const bf16x8*)(Wt + (long)row * EMB + ks * 32 + kg * 8);
        }
#pragma unroll
        for (int mf = 0; mf < 4; ++mf)
#pragma unroll
            for (int nf = 0; nf < 4; ++nf)
                acc[mf][nf] = __builtin_amdgcn_mfma_f32_16x16x32_bf16(a[mf], b[nf], acc[mf][nf], 0, 0, 0);
    }
#pragma unroll
    for (int mf = 0; mf < 4; ++mf) {
#pragma unroll
        for (int nf = 0; nf < 4; ++nf) {
            int col = n0 + nf * 16 + r;
#pragma unroll
            for (int j = 0; j < 4; ++j) {
                long row = m0 + mf * 16 + kg * 4 + j;
                if (row < nrows) xw[row * EMB + col] = f2bf(acc[mf][nf][j]);
            }
        }
    }
}

// ---------------- fused gather of hb and hi (dst contiguous) ----------------
__global__ void k_gather_hbhi(const ushort* __restrict__ src,
                              const int* __restrict__ bidx, const int* __restrict__ iidx,
                              ushort* __restrict__ dst) {
    int t = blockIdx.x * blockDim.x + threadIdx.x;
    int i = t >> 4;
    int d = (t & 15) << 3;
    if (i >= BATCH + N_SCORE) return;
    int r = (i < BATCH) ? bidx[i] : iidx[i - BATCH];
    *(uint4*)(dst + (long)i * EMB + d) = *(const uint4*)(src + (long)r * EMB + d);
}

// ---------------- out[2048, 50000] = hb @ hi^T via MFMA bf16 ----------------
// 1D grid, col-major decode + chunked XCD swizzle: each XCD owns a contiguous
// hi-column strip (~1.6MB, L2-resident) reused across all 16 hb row-blocks.
__global__ __launch_bounds__(256) void k_score_mfma(const ushort* __restrict__ A,
                                                    const ushort* __restrict__ B,
                                                    float* __restrict__ C) {
    const int q = SB_TOT / 8; // 782, exact
    int bid = blockIdx.x;
    int nb = (bid % 8) * q + bid / 8;   // bijective chunked swizzle
    int bx = nb / SB_Y;                 // consecutive nb share bx (same hi slice)
    int by = nb % SB_Y;

    int wid = threadIdx.x >> 6;
    int lane = threadIdx.x & 63;
    int wm = wid >> 1, wn = wid & 1;
    long m0 = (long)by * 128 + wm * 64;
    long n0 = (long)bx * 128 + wn * 64;
    int r = lane & 15;
    int kg = lane >> 4;

    f32x4 acc[4][4] = {};
#pragma unroll
    for (int ks = 0; ks < 4; ++ks) {
        bf16x8 a[4], b[4];
#pragma unroll
        for (int mf = 0; mf < 4; ++mf) {
            long row = m0 + mf * 16 + r;
            a[mf] = *(const bf16x8*)(A + row * EMB + ks * 32 + kg * 8);
        }
#pragma unroll
        for (int nf = 0; nf < 4; ++nf) {
            long row = n0 + nf * 16 + r;
            if (row >= N_SCORE) row = N_SCORE - 1;
            b[nf] = *(const bf16x8*)(B + row * EMB + ks * 32 + kg * 8);
        }
#pragma unroll
        for (int mf = 0; mf < 4; ++mf)
#pragma unroll
            for (int nf = 0; nf < 4; ++nf)
                acc[mf][nf] = __builtin_amdgcn_mfma_f32_16x16x32_bf16(a[mf], b[nf], acc[mf][nf], 0, 0, 0);
    }
#pragma unroll
    for (int mf = 0; mf < 4; ++mf) {
#pragma unroll
        for (int nf = 0; nf < 4; ++nf) {
            long col = n0 + nf * 16 + r;
            if (col < N_SCORE) {
#pragma unroll
                for (int j = 0; j < 4; ++j) {
                    long row = m0 + mf * 16 + kg * 4 + j;
                    __builtin_nontemporal_store(acc[mf][nf][j], &C[row * N_SCORE + col]);
                }
            }
        }
    }
}

extern "C" void kernel_launch(void* const* d_in, const int* in_sizes, int n_in,
                              void* d_out, int out_size, void* d_ws, size_t ws_size,
                              hipStream_t stream) {
    const float* emb_table      = (const float*)d_in[0];
    const float* W              = (const float*)d_in[1];
    const float* b              = (const float*)d_in[2];
    const float* sess_vals      = (const float*)d_in[3];
    const float* A_vals         = (const float*)d_in[4];
    const int*   batch_idxes    = (const int*)d_in[5];
    const int*   item_idxes     = (const int*)d_in[6];
    const int*   item_emb_idxes = (const int*)d_in[7];
    const int*   sess_rows      = (const int*)d_in[8];
    const int*   sess_cols      = (const int*)d_in[9];
    const int*   A_rows         = (const int*)d_in[10];
    const int*   A_cols         = (const int*)d_in[11];
    float* out = (float*)d_out;

    // -------- workspace layout (bytes), ~107 MB --------
    char* base = (char*)d_ws;
    ushort*   xb_item = (ushort*)(base + 0);            // [N_ITEMS,128] bf16, 12.8MB
    ushort*   xw      = (ushort*)(base + 12800000L);    // [N_TOTAL,128] bf16, 25.6MB
    ushort*   h1      = (ushort*)(base + 38400000L);    // [N_TOTAL,128] bf16, 25.6MB
    int2*     edgA    = (int2*)  (base + 64000000L);    // up to 3.2M x 8B
    int2*     edgS    = (int2*)  (base + 89600000L);    // 500K x 8B
    ushort*   Wt      = (ushort*)(base + 93600000L);    // 128x128 bf16
    ushort*   hb      = (ushort*)(base + 93632768L);    // [BATCH,128] bf16
    ushort*   hi      = (ushort*)(base + 94157056L);    // [N_SCORE,128] bf16, contiguous after hb
    // zeroed-together region: bm | cntBS | cntBA
    unsigned* bm      = (unsigned*)(base + 106957056L); // 3136 words
    int*      cntBS   = (int*)   (base + 106969600L);   // NB_S
    int*      cntBA   = (int*)   (base + 106972728L);   // NB_A
    int*      gtailS  = (int*)   (base + 106978984L);   // NB_S
    int*      gtailA  = (int*)   (base + 106982112L);   // NB_A

    ushort* xw_item = xw + (long)N_SESS * EMB;  // item half of xw

    // ---- zero bm + both bucket counters in one memset ----
    hipMemsetAsync(bm, 0, 106978984L - 106957056L, stream);
    // ---- mark needed h1 rows (both index sets, one launch) ----
    k_mark2<<<(BATCH + N_SCORE + 255) / 256, 256, 0, stream>>>(batch_idxes, BATCH,
                                                               item_idxes, N_SCORE, bm);
    // ---- fused histogram (S unfiltered + A filtered) ----
    k_hist2<<<NBLK_S + NBLK_A, 256, 0, stream>>>(sess_rows, cntBS, A_rows, cntBA, bm);
    // ---- fused scans ----
    k_scan2<<<2, 1024, 0, stream>>>(cntBS, gtailS, cntBA, gtailA);
    // ---- fused placement ----
    k_place2<<<NBLK_S + NBLK_A, 256, 0, stream>>>(sess_rows, sess_cols, sess_vals, gtailS, edgS,
                                                  A_rows, A_cols, A_vals, gtailA, edgA, bm);
    // ---- gather item embeddings (bf16) + W transpose (fused) ----
    k_gather_items_convW<<<(N_ITEMS * 32) / 256 + 64, 256, 0, stream>>>(emb_table, item_emb_idxes,
                                                                        xb_item, W, Wt);
    // ---- xw_item = x_item @ W (MFMA, M=50K) ----
    k_xw_mfma<<<(N_ITEMS + 127) / 128, 256, 0, stream>>>(xb_item, Wt, xw_item, N_ITEMS);
    // ---- spmm1 (reordered): xw[0:N_SESS] = S @ xw_item ----
    k_spmm_sorted<<<NB_S, 512, 0, stream>>>(gtailS, edgS, xw_item, xw, nullptr, N_SESS, nullptr);
    // ---- spmm2 + fused bias -> h1 (only needed rows written) ----
    k_spmm_sorted<<<NB_A, 512, 0, stream>>>(gtailA, edgA, xw, h1, b, N_TOTAL, bm);
    // ---- fused gather hb|hi ----
    k_gather_hbhi<<<((BATCH + N_SCORE) * 16 + 255) / 256, 256, 0, stream>>>(h1, batch_idxes,
                                                                            item_idxes, hb);
    // ---- score (1D grid, XCD-swizzled) ----
    k_score_mfma<<<SB_TOT, 256, 0, stream>>>(hb, hi, out);
}

// Round 9
// 410.077 us; speedup vs baseline: 7.6180x; 1.0772x over previous
//
#include <hip/hip_runtime.h>

#define EMB 128
#define N_ITEMS 50000
#define N_SESS 50000
#define N_TOTAL 100000
#define NNZ_S 500000
#define NNZ_A 3200000
#define BATCH 2048
#define N_SCORE 50000

#define RPB 64                                 // rows per bucket
#define NB_A ((N_TOTAL + RPB - 1) / RPB)       // 1563
#define NB_S ((N_SESS + RPB - 1) / RPB)        // 782
#define NBMAX 1600
#define EPT 8
#define EPB (256 * EPT)                        // 2048 edges per block (build kernels)
#define NBLK_S ((NNZ_S + EPB - 1) / EPB)       // 245
#define NBLK_A ((NNZ_A + EPB - 1) / EPB)       // 1563
#define GATHER_BLKS ((N_ITEMS * 32) / 256)     // 6250 (exact)
#define XW_BLKS ((N_ITEMS + 127) / 128)        // 391
#define CHUNK 4096                             // edges staged per sort pass

#define SB_X ((N_SCORE + 127) / 128)           // 391
#define SB_Y (BATCH / 128)                     // 16
#define SB_TOT (SB_X * SB_Y)                   // 6256 = 8 * 782

typedef __attribute__((ext_vector_type(8))) short bf16x8;
typedef __attribute__((ext_vector_type(4))) float f32x4;

__device__ inline ushort f2bf(float f) {
    unsigned u = __float_as_uint(f);
    unsigned r = (u + 0x7fff + ((u >> 16) & 1)) >> 16;
    return (ushort)r;
}
__device__ inline float bflo(unsigned u) { return __uint_as_float(u << 16); }
__device__ inline float bfhi(unsigned u) { return __uint_as_float(u & 0xffff0000u); }

// ---------------- mark needed h1 rows (both index arrays in one launch) ----------------
__global__ void k_mark2(const int* __restrict__ a, int na, const int* __restrict__ b, int nb_,
                        unsigned* __restrict__ bm) {
    int i = blockIdx.x * 256 + threadIdx.x;
    int r = -1;
    if (i < na) r = a[i];
    else if (i < na + nb_) r = b[i - na];
    if (r >= 0) atomicOr(&bm[r >> 5], 1u << (r & 31));
}

// ---------------- MEGA1: bucket histograms (S, A-filtered) + item gather + W transpose ----------------
__global__ __launch_bounds__(256) void k_mega1(const int* __restrict__ sRows, int* __restrict__ cntS,
                                               const int* __restrict__ aRows, int* __restrict__ cntA,
                                               const unsigned* __restrict__ bm,
                                               const float* __restrict__ emb,
                                               const int* __restrict__ emb_idx,
                                               ushort* __restrict__ xb_item,
                                               const float* __restrict__ W, ushort* __restrict__ Wt) {
    __shared__ int h[NBMAX];
    int blk = blockIdx.x;
    int tid = threadIdx.x;
    if (blk < NBLK_S + NBLK_A) {
        // ---- histogram ----
        const int* rows;
        int* cnt;
        const unsigned* filt;
        int nnz, nb;
        long b0;
        if (blk < NBLK_S) {
            rows = sRows; cnt = cntS; filt = nullptr; nnz = NNZ_S; nb = NB_S;
            b0 = (long)blk * EPB;
        } else {
            rows = aRows; cnt = cntA; filt = bm; nnz = NNZ_A; nb = NB_A;
            b0 = (long)(blk - NBLK_S) * EPB;
        }
        for (int i = tid; i < nb; i += 256) h[i] = 0;
        __syncthreads();
#pragma unroll
        for (int j = 0; j < EPT; ++j) {
            long e = b0 + j * 256 + tid;
            if (e < nnz) {
                int r = rows[e];
                if (!filt || ((filt[r >> 5] >> (r & 31)) & 1))
                    atomicAdd(&h[r >> 6], 1);
            }
        }
        __syncthreads();
        for (int i = tid; i < nb; i += 256) {
            int v = h[i];
            if (v) atomicAdd(&cnt[i], v);
        }
    } else if (blk < NBLK_S + NBLK_A + GATHER_BLKS) {
        // ---- gather x_item = bf16(emb[idx]) ----
        int t = (blk - NBLK_S - NBLK_A) * 256 + tid;
        int i = t >> 5;
        int d = (t & 31) << 2;
        float4 v = *(const float4*)(emb + (long)emb_idx[i] * EMB + d);
        uint2 o;
        o.x = (unsigned)f2bf(v.x) | ((unsigned)f2bf(v.y) << 16);
        o.y = (unsigned)f2bf(v.z) | ((unsigned)f2bf(v.w) << 16);
        *(uint2*)(xb_item + (long)i * EMB + d) = o;
    } else {
        // ---- W transpose (64 blocks) ----
        int i = (blk - NBLK_S - NBLK_A - GATHER_BLKS) * 256 + tid;
        int n = i >> 7, k = i & 127;
        Wt[n * 128 + k] = f2bf(W[k * 128 + n]);
    }
}

// ---------------- fused scan: block 0 -> S, block 1 -> A ----------------
__global__ __launch_bounds__(1024) void k_scan2(const int* __restrict__ cntS, int* __restrict__ offS,
                                                const int* __restrict__ cntA, int* __restrict__ offA) {
    __shared__ int wsum[16];
    __shared__ int carry_s;
    const int* cnt = blockIdx.x ? cntA : cntS;
    int* off = blockIdx.x ? offA : offS;
    int n = blockIdx.x ? NB_A : NB_S;
    int tid = threadIdx.x, lane = tid & 63, wid = tid >> 6;
    if (tid == 0) carry_s = 0;
    __syncthreads();
    for (int base = 0; base < n; base += 1024) {
        int i = base + tid;
        int v = (i < n) ? cnt[i] : 0;
        int x = v;
#pragma unroll
        for (int s = 1; s < 64; s <<= 1) {
            int t = __shfl_up(x, s, 64);
            if (lane >= s) x += t;
        }
        if (lane == 63) wsum[wid] = x;
        __syncthreads();
        if (wid == 0) {
            int y = (lane < 16) ? wsum[lane] : 0;
#pragma unroll
            for (int s = 1; s < 16; s <<= 1) {
                int t = __shfl_up(y, s, 64);
                if (lane >= s) y += t;
            }
            if (lane < 16) wsum[lane] = y;
        }
        __syncthreads();
        int carry = carry_s;
        int wofs = (wid == 0) ? 0 : wsum[wid - 1];
        if (i < n) off[i] = carry + wofs + x - v;
        __syncthreads();
        if (tid == 0) carry_s = carry + wsum[15];
        __syncthreads();
    }
}

// ---------------- MEGA2: bucketed placement (S + A) + xw_item = x_item @ W ----------------
// edge packed: key = (row & 63) << 17 | col, val as int bits
__global__ __launch_bounds__(256) void k_mega2(const int* __restrict__ sRows, const int* __restrict__ sCols,
                                               const float* __restrict__ sVals, int* __restrict__ gtailS,
                                               int2* __restrict__ edgS,
                                               const int* __restrict__ aRows, const int* __restrict__ aCols,
                                               const float* __restrict__ aVals, int* __restrict__ gtailA,
                                               int2* __restrict__ edgA,
                                               const unsigned* __restrict__ bm,
                                               const ushort* __restrict__ xb_item,
                                               const ushort* __restrict__ Wt,
                                               ushort* __restrict__ xw_item) {
    __shared__ int h[NBMAX];
    __shared__ int base_s[NBMAX];
    int blk = blockIdx.x;
    int tid = threadIdx.x;
    if (blk < NBLK_S + NBLK_A) {
        // ---- placement ----
        const int *rows, *cols;
        const float* vals;
        int* gtail;
        int2* out;
        const unsigned* filt;
        int nnz, nb;
        long b0;
        if (blk < NBLK_S) {
            rows = sRows; cols = sCols; vals = sVals; gtail = gtailS; out = edgS;
            filt = nullptr; nnz = NNZ_S; nb = NB_S;
            b0 = (long)blk * EPB;
        } else {
            rows = aRows; cols = aCols; vals = aVals; gtail = gtailA; out = edgA;
            filt = bm; nnz = NNZ_A; nb = NB_A;
            b0 = (long)(blk - NBLK_S) * EPB;
        }
        for (int i = tid; i < nb; i += 256) h[i] = 0;
        __syncthreads();
        int er[EPT], ec[EPT];
        float ev[EPT];
#pragma unroll
        for (int j = 0; j < EPT; ++j) {
            long e = b0 + j * 256 + tid;
            er[j] = -1;
            if (e < nnz) {
                int r = rows[e];
                if (!filt || ((filt[r >> 5] >> (r & 31)) & 1)) {
                    er[j] = r;
                    ec[j] = cols[e];
                    ev[j] = vals[e];
                    atomicAdd(&h[r >> 6], 1);
                }
            }
        }
        __syncthreads();
        for (int i = tid; i < nb; i += 256) {
            int v = h[i];
            if (v) base_s[i] = atomicAdd(&gtail[i], v);
            h[i] = 0; // reuse as local cursor
        }
        __syncthreads();
#pragma unroll
        for (int j = 0; j < EPT; ++j) {
            if (er[j] >= 0) {
                int bk = er[j] >> 6;
                int loc = atomicAdd(&h[bk], 1);
                out[base_s[bk] + loc] = make_int2(((er[j] & 63) << 17) | ec[j], __float_as_int(ev[j]));
            }
        }
    } else {
        // ---- xw_item = xb_item @ Wt^T via MFMA (M = N_ITEMS) ----
        int bid = blk - NBLK_S - NBLK_A;
        int wid = tid >> 6;
        int lane = tid & 63;
        int wm = wid >> 1, wn = wid & 1;
        long m0 = (long)bid * 128 + wm * 64;
        int n0 = wn * 64;
        int r = lane & 15;
        int kg = lane >> 4;

        f32x4 acc[4][4] = {};
#pragma unroll
        for (int ks = 0; ks < 4; ++ks) {
            bf16x8 a[4], b[4];
#pragma unroll
            for (int mf = 0; mf < 4; ++mf) {
                long row = m0 + mf * 16 + r;
                if (row >= N_ITEMS) row = N_ITEMS - 1;
                a[mf] = *(const bf16x8*)(xb_item + row * EMB + ks * 32 + kg * 8);
            }
#pragma unroll
            for (int nf = 0; nf < 4; ++nf) {
                int row = n0 + nf * 16 + r;
                b[nf] = *(const bf16x8*)(Wt + (long)row * EMB + ks * 32 + kg * 8);
            }
#pragma unroll
            for (int mf = 0; mf < 4; ++mf)
#pragma unroll
                for (int nf = 0; nf < 4; ++nf)
                    acc[mf][nf] = __builtin_amdgcn_mfma_f32_16x16x32_bf16(a[mf], b[nf], acc[mf][nf], 0, 0, 0);
        }
#pragma unroll
        for (int mf = 0; mf < 4; ++mf) {
#pragma unroll
            for (int nf = 0; nf < 4; ++nf) {
                int col = n0 + nf * 16 + r;
#pragma unroll
                for (int j = 0; j < 4; ++j) {
                    long row = m0 + mf * 16 + kg * 4 + j;
                    if (row < N_ITEMS) xw_item[row * EMB + col] = f2bf(acc[mf][nf][j]);
                }
            }
        }
    }
}

// ---------------- sorted-bucket SpMM: counting-sort in LDS, register accumulation ----------------
__global__ __launch_bounds__(512) void k_spmm_sorted(const int* __restrict__ gtail,
                                                     const int2* __restrict__ edges,
                                                     const ushort* __restrict__ src,
                                                     ushort* __restrict__ dst,
                                                     const float* __restrict__ bias,
                                                     int nrows,
                                                     const unsigned* __restrict__ bm) {
    __shared__ int2 se[CHUNK];      // 32 KB sorted edge buffer
    __shared__ int hist[RPB], sofs[RPB], cur[RPB];
    int tid = threadIdx.x, lane = tid & 63, w = tid >> 6;
    int bk = blockIdx.x;
    int begin = bk ? gtail[bk - 1] : 0;
    int end = gtail[bk];

    float2 acc[8] = {};
    for (int cbase = begin; cbase < end; cbase += CHUNK) {
        int m = end - cbase;
        if (m > CHUNK) m = CHUNK;
        if (tid < RPB) hist[tid] = 0;
        __syncthreads();
        int2 er[CHUNK / 512];
#pragma unroll
        for (int j = 0; j < CHUNK / 512; ++j) {
            int idx = j * 512 + tid;
            if (idx < m) {
                er[j] = edges[cbase + idx];
                atomicAdd(&hist[er[j].x >> 17], 1);
            } else {
                er[j].x = -1;
            }
        }
        __syncthreads();
        if (w == 0) {
            int v = hist[lane];
            int x = v;
#pragma unroll
            for (int s = 1; s < 64; s <<= 1) {
                int t = __shfl_up(x, s, 64);
                if (lane >= s) x += t;
            }
            sofs[lane] = x - v;
            cur[lane] = x - v;
        }
        __syncthreads();
#pragma unroll
        for (int j = 0; j < CHUNK / 512; ++j) {
            if (er[j].x >= 0) {
                int lr = er[j].x >> 17;
                int p = atomicAdd(&cur[lr], 1);
                se[p] = er[j];
            }
        }
        __syncthreads();
#pragma unroll
        for (int i = 0; i < 8; ++i) {
            int lr = w * 8 + i;
            int e = sofs[lr];
            int s1 = e + hist[lr];
            for (; e + 4 <= s1; e += 4) {
                int2 e0 = se[e], e1 = se[e + 1], e2 = se[e + 2], e3 = se[e + 3];
                unsigned u0 = *(const unsigned*)(src + (long)(e0.x & 0x1FFFF) * EMB + lane * 2);
                unsigned u1 = *(const unsigned*)(src + (long)(e1.x & 0x1FFFF) * EMB + lane * 2);
                unsigned u2 = *(const unsigned*)(src + (long)(e2.x & 0x1FFFF) * EMB + lane * 2);
                unsigned u3 = *(const unsigned*)(src + (long)(e3.x & 0x1FFFF) * EMB + lane * 2);
                float v0 = __int_as_float(e0.y), v1 = __int_as_float(e1.y);
                float v2 = __int_as_float(e2.y), v3 = __int_as_float(e3.y);
                acc[i].x += v0 * bflo(u0) + v1 * bflo(u1) + v2 * bflo(u2) + v3 * bflo(u3);
                acc[i].y += v0 * bfhi(u0) + v1 * bfhi(u1) + v2 * bfhi(u2) + v3 * bfhi(u3);
            }
            for (; e < s1; ++e) {
                int2 e0 = se[e];
                unsigned u0 = *(const unsigned*)(src + (long)(e0.x & 0x1FFFF) * EMB + lane * 2);
                float v0 = __int_as_float(e0.y);
                acc[i].x += v0 * bflo(u0);
                acc[i].y += v0 * bfhi(u0);
            }
        }
        __syncthreads();
    }
#pragma unroll
    for (int i = 0; i < 8; ++i) {
        int r = bk * RPB + w * 8 + i;
        if (r < nrows && (!bm || ((bm[r >> 5] >> (r & 31)) & 1))) {
            float a = acc[i].x, c = acc[i].y;
            if (bias) {
                a += bias[lane * 2];
                c += bias[lane * 2 + 1];
            }
            unsigned o = (unsigned)f2bf(a) | ((unsigned)f2bf(c) << 16);
            *((unsigned*)(dst + (long)r * EMB) + lane) = o;
        }
    }
}

// ---------------- out[2048, 50000] = h1[bidx] @ h1[iidx]^T via MFMA (inline gather) ----------------
// 1D grid, col-major decode + chunked XCD swizzle: each XCD owns a contiguous
// column strip whose h1 working set (~2.1MB) is L2-resident across all 16 row-blocks.
__global__ __launch_bounds__(256) void k_score_mfma(const ushort* __restrict__ H,
                                                    const int* __restrict__ bidx,
                                                    const int* __restrict__ iidx,
                                                    float* __restrict__ C) {
    const int q = SB_TOT / 8; // 782, exact
    int bid = blockIdx.x;
    int nb = (bid % 8) * q + bid / 8;   // bijective chunked swizzle
    int bx = nb / SB_Y;                 // consecutive nb share bx (same hi slice)
    int by = nb % SB_Y;

    int wid = threadIdx.x >> 6;
    int lane = threadIdx.x & 63;
    int wm = wid >> 1, wn = wid & 1;
    long m0 = (long)by * 128 + wm * 64;
    long n0 = (long)bx * 128 + wn * 64;
    int r = lane & 15;
    int kg = lane >> 4;

    // hoist the row-index gathers out of the K loop
    long arow[4], brow[4];
#pragma unroll
    for (int mf = 0; mf < 4; ++mf) arow[mf] = bidx[m0 + mf * 16 + r];
#pragma unroll
    for (int nf = 0; nf < 4; ++nf) {
        long row = n0 + nf * 16 + r;
        if (row >= N_SCORE) row = N_SCORE - 1; // clamp: safe load, stores guarded
        brow[nf] = iidx[row];
    }

    f32x4 acc[4][4] = {};
#pragma unroll
    for (int ks = 0; ks < 4; ++ks) {
        bf16x8 a[4], b[4];
#pragma unroll
        for (int mf = 0; mf < 4; ++mf)
            a[mf] = *(const bf16x8*)(H + arow[mf] * EMB + ks * 32 + kg * 8);
#pragma unroll
        for (int nf = 0; nf < 4; ++nf)
            b[nf] = *(const bf16x8*)(H + brow[nf] * EMB + ks * 32 + kg * 8);
#pragma unroll
        for (int mf = 0; mf < 4; ++mf)
#pragma unroll
            for (int nf = 0; nf < 4; ++nf)
                acc[mf][nf] = __builtin_amdgcn_mfma_f32_16x16x32_bf16(a[mf], b[nf], acc[mf][nf], 0, 0, 0);
    }
#pragma unroll
    for (int mf = 0; mf < 4; ++mf) {
#pragma unroll
        for (int nf = 0; nf < 4; ++nf) {
            long col = n0 + nf * 16 + r;
            if (col < N_SCORE) {
#pragma unroll
                for (int j = 0; j < 4; ++j) {
                    long row = m0 + mf * 16 + kg * 4 + j;
                    __builtin_nontemporal_store(acc[mf][nf][j], &C[row * N_SCORE + col]);
                }
            }
        }
    }
}

extern "C" void kernel_launch(void* const* d_in, const int* in_sizes, int n_in,
                              void* d_out, int out_size, void* d_ws, size_t ws_size,
                              hipStream_t stream) {
    const float* emb_table      = (const float*)d_in[0];
    const float* W              = (const float*)d_in[1];
    const float* b              = (const float*)d_in[2];
    const float* sess_vals      = (const float*)d_in[3];
    const float* A_vals         = (const float*)d_in[4];
    const int*   batch_idxes    = (const int*)d_in[5];
    const int*   item_idxes     = (const int*)d_in[6];
    const int*   item_emb_idxes = (const int*)d_in[7];
    const int*   sess_rows      = (const int*)d_in[8];
    const int*   sess_cols      = (const int*)d_in[9];
    const int*   A_rows         = (const int*)d_in[10];
    const int*   A_cols         = (const int*)d_in[11];
    float* out = (float*)d_out;

    // -------- workspace layout (bytes), ~107 MB --------
    char* base = (char*)d_ws;
    ushort*   xb_item = (ushort*)(base + 0);            // [N_ITEMS,128] bf16, 12.8MB
    ushort*   xw      = (ushort*)(base + 12800000L);    // [N_TOTAL,128] bf16, 25.6MB
    ushort*   h1      = (ushort*)(base + 38400000L);    // [N_TOTAL,128] bf16, 25.6MB
    int2*     edgA    = (int2*)  (base + 64000000L);    // up to 3.2M x 8B
    int2*     edgS    = (int2*)  (base + 89600000L);    // 500K x 8B
    ushort*   Wt      = (ushort*)(base + 93600000L);    // 128x128 bf16
    // zeroed-together region: bm | cntBS | cntBA
    unsigned* bm      = (unsigned*)(base + 106957056L); // 3136 words
    int*      cntBS   = (int*)   (base + 106969600L);   // NB_S
    int*      cntBA   = (int*)   (base + 106972728L);   // NB_A
    int*      gtailS  = (int*)   (base + 106978984L);   // NB_S
    int*      gtailA  = (int*)   (base + 106982112L);   // NB_A

    ushort* xw_item = xw + (long)N_SESS * EMB;  // item half of xw

    // ---- zero bm + both bucket counters in one memset ----
    hipMemsetAsync(bm, 0, 106978984L - 106957056L, stream);
    // ---- mark needed h1 rows (both index sets, one launch) ----
    k_mark2<<<(BATCH + N_SCORE + 255) / 256, 256, 0, stream>>>(batch_idxes, BATCH,
                                                               item_idxes, N_SCORE, bm);
    // ---- MEGA1: hist(S,A) + item gather + convW ----
    k_mega1<<<NBLK_S + NBLK_A + GATHER_BLKS + 64, 256, 0, stream>>>(
        sess_rows, cntBS, A_rows, cntBA, bm,
        emb_table, item_emb_idxes, xb_item, W, Wt);
    // ---- fused scans ----
    k_scan2<<<2, 1024, 0, stream>>>(cntBS, gtailS, cntBA, gtailA);
    // ---- MEGA2: place(S,A) + xw_item = x_item @ W ----
    k_mega2<<<NBLK_S + NBLK_A + XW_BLKS, 256, 0, stream>>>(
        sess_rows, sess_cols, sess_vals, gtailS, edgS,
        A_rows, A_cols, A_vals, gtailA, edgA, bm,
        xb_item, Wt, xw_item);
    // ---- spmm1 (reordered): xw[0:N_SESS] = S @ xw_item ----
    k_spmm_sorted<<<NB_S, 512, 0, stream>>>(gtailS, edgS, xw_item, xw, nullptr, N_SESS, nullptr);
    // ---- spmm2 + fused bias -> h1 (only needed rows written) ----
    k_spmm_sorted<<<NB_A, 512, 0, stream>>>(gtailA, edgA, xw, h1, b, N_TOTAL, bm);
    // ---- score (1D grid, XCD-swizzled, inline hb/hi gather) ----
    k_score_mfma<<<SB_TOT, 256, 0, stream>>>(h1, batch_idxes, item_idxes, out);
}

// Round 10
// 354.114 us; speedup vs baseline: 8.8219x; 1.1580x over previous
//
#include <hip/hip_runtime.h>

#define EMB 128
#define N_ITEMS 50000
#define N_SESS 50000
#define N_TOTAL 100000
#define NNZ_S 500000
#define NNZ_A 3200000
#define BATCH 2048
#define N_SCORE 50000

#define RPB 64                                 // rows per bucket
#define NB_A ((N_TOTAL + RPB - 1) / RPB)       // 1563
#define NB_S ((N_SESS + RPB - 1) / RPB)        // 782
#define NBMAX 1600
#define EPT 8
#define EPB (256 * EPT)                        // 2048 edges per build block
#define NBLK_S ((NNZ_S + EPB - 1) / EPB)       // 245
#define NBLK_A ((NNZ_A + EPB - 1) / EPB)       // 1563
#define XW_BLKS ((N_ITEMS + 127) / 128)        // 391
#define CHUNK 4096                             // edges staged per sort pass

#define STRIDE_S 1024                          // slots per S bucket (mean 640, sd 25)
#define STRIDE_A 2560                          // slots per A bucket (mean 2048, sd 45; filtered ~41%)

#define MARK_BLKS ((BATCH + N_SCORE + 255) / 256)  // 204

#define SB_X ((N_SCORE + 127) / 128)           // 391
#define SB_Y (BATCH / 256)                     // 8
#define SB_TOT (SB_X * SB_Y)                   // 3128 = 8 * 391

typedef __attribute__((ext_vector_type(8))) short bf16x8;
typedef __attribute__((ext_vector_type(4))) float f32x4;

__device__ inline ushort f2bf(float f) {
    unsigned u = __float_as_uint(f);
    unsigned r = (u + 0x7fff + ((u >> 16) & 1)) >> 16;
    return (ushort)r;
}
__device__ inline float bflo(unsigned u) { return __uint_as_float(u << 16); }
__device__ inline float bfhi(unsigned u) { return __uint_as_float(u & 0xffff0000u); }

// ---------------- PREP: mark needed h1 rows + W transpose ----------------
__global__ __launch_bounds__(256) void k_prep(const int* __restrict__ bidx, const int* __restrict__ iidx,
                                              unsigned* __restrict__ bm,
                                              const float* __restrict__ W, ushort* __restrict__ Wt) {
    int blk = blockIdx.x;
    int tid = threadIdx.x;
    if (blk < MARK_BLKS) {
        int i = blk * 256 + tid;
        int r = -1;
        if (i < BATCH) r = bidx[i];
        else if (i < BATCH + N_SCORE) r = iidx[i - BATCH];
        if (r >= 0) atomicOr(&bm[r >> 5], 1u << (r & 31));
    } else {
        int i = (blk - MARK_BLKS) * 256 + tid;
        int n = i >> 7, k = i & 127;
        Wt[n * 128 + k] = f2bf(W[k * 128 + n]);
    }
}

// ---------------- BUILD: strided bucketed placement (S + A-filtered) + fused-gather xw GEMM ----------------
// edge packed: key = (row & 63) << 17 | col, val as int bits
__global__ __launch_bounds__(256) void k_build(const int* __restrict__ sRows, const int* __restrict__ sCols,
                                               const float* __restrict__ sVals, int* __restrict__ tailS,
                                               int2* __restrict__ edgS,
                                               const int* __restrict__ aRows, const int* __restrict__ aCols,
                                               const float* __restrict__ aVals, int* __restrict__ tailA,
                                               int2* __restrict__ edgA,
                                               const unsigned* __restrict__ bm,
                                               const float* __restrict__ emb,
                                               const int* __restrict__ emb_idx,
                                               const ushort* __restrict__ Wt,
                                               ushort* __restrict__ xw_item) {
    __shared__ int h[NBMAX];
    __shared__ int base_s[NBMAX];
    int blk = blockIdx.x;
    int tid = threadIdx.x;
    if (blk < NBLK_S + NBLK_A) {
        // ---- placement (strided regions, no scan needed) ----
        const int *rows, *cols;
        const float* vals;
        int* tail;
        int2* out;
        const unsigned* filt;
        int nnz, nb, stride;
        long b0;
        if (blk < NBLK_S) {
            rows = sRows; cols = sCols; vals = sVals; tail = tailS; out = edgS;
            filt = nullptr; nnz = NNZ_S; nb = NB_S; stride = STRIDE_S;
            b0 = (long)blk * EPB;
        } else {
            rows = aRows; cols = aCols; vals = aVals; tail = tailA; out = edgA;
            filt = bm; nnz = NNZ_A; nb = NB_A; stride = STRIDE_A;
            b0 = (long)(blk - NBLK_S) * EPB;
        }
        for (int i = tid; i < nb; i += 256) h[i] = 0;
        __syncthreads();
        int er[EPT], ec[EPT];
        float ev[EPT];
#pragma unroll
        for (int j = 0; j < EPT; ++j) {
            long e = b0 + j * 256 + tid;
            er[j] = -1;
            if (e < nnz) {
                int r = rows[e];
                if (!filt || ((filt[r >> 5] >> (r & 31)) & 1)) {
                    er[j] = r;
                    ec[j] = cols[e];
                    ev[j] = vals[e];
                    atomicAdd(&h[r >> 6], 1);
                }
            }
        }
        __syncthreads();
        for (int i = tid; i < nb; i += 256) {
            int v = h[i];
            if (v) base_s[i] = atomicAdd(&tail[i], v);
            h[i] = 0; // reuse as local cursor
        }
        __syncthreads();
#pragma unroll
        for (int j = 0; j < EPT; ++j) {
            if (er[j] >= 0) {
                int bk = er[j] >> 6;
                int loc = base_s[bk] + atomicAdd(&h[bk], 1);
                if (loc < stride) // paranoia clamp (prob ~0; keeps writes in-buffer)
                    out[(long)bk * stride + loc] = make_int2(((er[j] & 63) << 17) | ec[j],
                                                             __float_as_int(ev[j]));
            }
        }
    } else {
        // ---- xw_item = bf16(emb[emb_idx]) @ Wt^T via MFMA (fused gather, M = N_ITEMS) ----
        int bid = blk - NBLK_S - NBLK_A;
        int wid = tid >> 6;
        int lane = tid & 63;
        int wm = wid >> 1, wn = wid & 1;
        long m0 = (long)bid * 128 + wm * 64;
        int n0 = wn * 64;
        int r = lane & 15;
        int kg = lane >> 4;

        long arow[4];
#pragma unroll
        for (int mf = 0; mf < 4; ++mf) {
            long row = m0 + mf * 16 + r;
            if (row >= N_ITEMS) row = N_ITEMS - 1; // clamp, stores guarded
            arow[mf] = emb_idx[row];
        }

        f32x4 acc[4][4] = {};
#pragma unroll
        for (int ks = 0; ks < 4; ++ks) {
            bf16x8 a[4], b[4];
#pragma unroll
            for (int mf = 0; mf < 4; ++mf) {
                const float* p = emb + arow[mf] * EMB + ks * 32 + kg * 8;
                float4 lo = *(const float4*)p;
                float4 hi = *(const float4*)(p + 4);
                bf16x8 t;
                t[0] = (short)f2bf(lo.x); t[1] = (short)f2bf(lo.y);
                t[2] = (short)f2bf(lo.z); t[3] = (short)f2bf(lo.w);
                t[4] = (short)f2bf(hi.x); t[5] = (short)f2bf(hi.y);
                t[6] = (short)f2bf(hi.z); t[7] = (short)f2bf(hi.w);
                a[mf] = t;
            }
#pragma unroll
            for (int nf = 0; nf < 4; ++nf) {
                int row = n0 + nf * 16 + r;
                b[nf] = *(const bf16x8*)(Wt + (long)row * EMB + ks * 32 + kg * 8);
            }
#pragma unroll
            for (int mf = 0; mf < 4; ++mf)
#pragma unroll
                for (int nf = 0; nf < 4; ++nf)
                    acc[mf][nf] = __builtin_amdgcn_mfma_f32_16x16x32_bf16(a[mf], b[nf], acc[mf][nf], 0, 0, 0);
        }
#pragma unroll
        for (int mf = 0; mf < 4; ++mf) {
#pragma unroll
            for (int nf = 0; nf < 4; ++nf) {
                int col = n0 + nf * 16 + r;
#pragma unroll
                for (int j = 0; j < 4; ++j) {
                    long row = m0 + mf * 16 + kg * 4 + j;
                    if (row < N_ITEMS) xw_item[row * EMB + col] = f2bf(acc[mf][nf][j]);
                }
            }
        }
    }
}

// ---------------- sorted-bucket SpMM over strided edge regions ----------------
__global__ __launch_bounds__(512) void k_spmm_sorted(const int* __restrict__ tail,
                                                     const int2* __restrict__ edges, int stride,
                                                     const ushort* __restrict__ src,
                                                     ushort* __restrict__ dst,
                                                     const float* __restrict__ bias,
                                                     int nrows,
                                                     const unsigned* __restrict__ bm) {
    __shared__ int2 se[CHUNK];      // 32 KB sorted edge buffer
    __shared__ int hist[RPB], sofs[RPB], cur[RPB];
    int tid = threadIdx.x, lane = tid & 63, w = tid >> 6;
    int bk = blockIdx.x;
    long begin = (long)bk * stride;
    int cnt = tail[bk];
    if (cnt > stride) cnt = stride;
    long end = begin + cnt;

    float2 acc[8] = {};
    for (long cbase = begin; cbase < end; cbase += CHUNK) {
        int m = (int)(end - cbase);
        if (m > CHUNK) m = CHUNK;
        if (tid < RPB) hist[tid] = 0;
        __syncthreads();
        int2 er[CHUNK / 512];
#pragma unroll
        for (int j = 0; j < CHUNK / 512; ++j) {
            int idx = j * 512 + tid;
            if (idx < m) {
                er[j] = edges[cbase + idx];
                atomicAdd(&hist[er[j].x >> 17], 1);
            } else {
                er[j].x = -1;
            }
        }
        __syncthreads();
        if (w == 0) {
            int v = hist[lane];
            int x = v;
#pragma unroll
            for (int s = 1; s < 64; s <<= 1) {
                int t = __shfl_up(x, s, 64);
                if (lane >= s) x += t;
            }
            sofs[lane] = x - v;
            cur[lane] = x - v;
        }
        __syncthreads();
#pragma unroll
        for (int j = 0; j < CHUNK / 512; ++j) {
            if (er[j].x >= 0) {
                int lr = er[j].x >> 17;
                int p = atomicAdd(&cur[lr], 1);
                se[p] = er[j];
            }
        }
        __syncthreads();
#pragma unroll
        for (int i = 0; i < 8; ++i) {
            int lr = w * 8 + i;
            int e = sofs[lr];
            int s1 = e + hist[lr];
            for (; e + 4 <= s1; e += 4) {
                int2 e0 = se[e], e1 = se[e + 1], e2 = se[e + 2], e3 = se[e + 3];
                unsigned u0 = *(const unsigned*)(src + (long)(e0.x & 0x1FFFF) * EMB + lane * 2);
                unsigned u1 = *(const unsigned*)(src + (long)(e1.x & 0x1FFFF) * EMB + lane * 2);
                unsigned u2 = *(const unsigned*)(src + (long)(e2.x & 0x1FFFF) * EMB + lane * 2);
                unsigned u3 = *(const unsigned*)(src + (long)(e3.x & 0x1FFFF) * EMB + lane * 2);
                float v0 = __int_as_float(e0.y), v1 = __int_as_float(e1.y);
                float v2 = __int_as_float(e2.y), v3 = __int_as_float(e3.y);
                acc[i].x += v0 * bflo(u0) + v1 * bflo(u1) + v2 * bflo(u2) + v3 * bflo(u3);
                acc[i].y += v0 * bfhi(u0) + v1 * bfhi(u1) + v2 * bfhi(u2) + v3 * bfhi(u3);
            }
            for (; e < s1; ++e) {
                int2 e0 = se[e];
                unsigned u0 = *(const unsigned*)(src + (long)(e0.x & 0x1FFFF) * EMB + lane * 2);
                float v0 = __int_as_float(e0.y);
                acc[i].x += v0 * bflo(u0);
                acc[i].y += v0 * bfhi(u0);
            }
        }
        __syncthreads();
    }
#pragma unroll
    for (int i = 0; i < 8; ++i) {
        int r = bk * RPB + w * 8 + i;
        if (r < nrows && (!bm || ((bm[r >> 5] >> (r & 31)) & 1))) {
            float a = acc[i].x, c = acc[i].y;
            if (bias) {
                a += bias[lane * 2];
                c += bias[lane * 2 + 1];
            }
            unsigned o = (unsigned)f2bf(a) | ((unsigned)f2bf(c) << 16);
            *((unsigned*)(dst + (long)r * EMB) + lane) = o;
        }
    }
}

// ---------------- out[2048, 50000] = h1[bidx] @ h1[iidx]^T via MFMA (inline gather) ----------------
// 512 threads, 256x128 tile (8 waves as 4m x 2n), 1D grid, col-major + chunked XCD swizzle.
__global__ __launch_bounds__(512) void k_score_mfma(const ushort* __restrict__ H,
                                                    const int* __restrict__ bidx,
                                                    const int* __restrict__ iidx,
                                                    float* __restrict__ C) {
    const int q = SB_TOT / 8; // 391, exact
    int bid = blockIdx.x;
    int nb = (bid % 8) * q + bid / 8;   // bijective chunked swizzle
    int bx = nb / SB_Y;                 // consecutive nb share bx (same hi slice)
    int by = nb % SB_Y;

    int wid = threadIdx.x >> 6;
    int lane = threadIdx.x & 63;
    int wm = wid >> 1, wn = wid & 1;    // wm 0..3, wn 0..1
    long m0 = (long)by * 256 + wm * 64;
    long n0 = (long)bx * 128 + wn * 64;
    int r = lane & 15;
    int kg = lane >> 4;

    long arow[4], brow[4];
#pragma unroll
    for (int mf = 0; mf < 4; ++mf) arow[mf] = bidx[m0 + mf * 16 + r];
#pragma unroll
    for (int nf = 0; nf < 4; ++nf) {
        long row = n0 + nf * 16 + r;
        if (row >= N_SCORE) row = N_SCORE - 1; // clamp: safe load, stores guarded
        brow[nf] = iidx[row];
    }

    f32x4 acc[4][4] = {};
#pragma unroll
    for (int ks = 0; ks < 4; ++ks) {
        bf16x8 a[4], b[4];
#pragma unroll
        for (int mf = 0; mf < 4; ++mf)
            a[mf] = *(const bf16x8*)(H + arow[mf] * EMB + ks * 32 + kg * 8);
#pragma unroll
        for (int nf = 0; nf < 4; ++nf)
            b[nf] = *(const bf16x8*)(H + brow[nf] * EMB + ks * 32 + kg * 8);
#pragma unroll
        for (int mf = 0; mf < 4; ++mf)
#pragma unroll
            for (int nf = 0; nf < 4; ++nf)
                acc[mf][nf] = __builtin_amdgcn_mfma_f32_16x16x32_bf16(a[mf], b[nf], acc[mf][nf], 0, 0, 0);
    }
#pragma unroll
    for (int mf = 0; mf < 4; ++mf) {
#pragma unroll
        for (int nf = 0; nf < 4; ++nf) {
            long col = n0 + nf * 16 + r;
            if (col < N_SCORE) {
#pragma unroll
                for (int j = 0; j < 4; ++j) {
                    long row = m0 + mf * 16 + kg * 4 + j;
                    __builtin_nontemporal_store(acc[mf][nf][j], &C[row * N_SCORE + col]);
                }
            }
        }
    }
}

extern "C" void kernel_launch(void* const* d_in, const int* in_sizes, int n_in,
                              void* d_out, int out_size, void* d_ws, size_t ws_size,
                              hipStream_t stream) {
    const float* emb_table      = (const float*)d_in[0];
    const float* W              = (const float*)d_in[1];
    const float* b              = (const float*)d_in[2];
    const float* sess_vals      = (const float*)d_in[3];
    const float* A_vals         = (const float*)d_in[4];
    const int*   batch_idxes    = (const int*)d_in[5];
    const int*   item_idxes     = (const int*)d_in[6];
    const int*   item_emb_idxes = (const int*)d_in[7];
    const int*   sess_rows      = (const int*)d_in[8];
    const int*   sess_cols      = (const int*)d_in[9];
    const int*   A_rows         = (const int*)d_in[10];
    const int*   A_cols         = (const int*)d_in[11];
    float* out = (float*)d_out;

    // -------- workspace layout (bytes), ~90 MB --------
    char* base = (char*)d_ws;
    ushort*   xw    = (ushort*)(base + 0);            // [N_TOTAL,128] bf16, 25.6MB
    ushort*   h1    = (ushort*)(base + 25600000L);    // [N_TOTAL,128] bf16, 25.6MB
    int2*     edgA  = (int2*)  (base + 51200000L);    // NB_A x STRIDE_A x 8B = 32.0MB
    int2*     edgS  = (int2*)  (base + 83210240L);    // NB_S x STRIDE_S x 8B = 6.4MB
    ushort*   Wt    = (ushort*)(base + 89616384L);    // 128x128 bf16, 32KB
    // zeroed-together region: bm | tailS | tailA
    unsigned* bm    = (unsigned*)(base + 89649152L);  // 3136 words
    int*      tailS = (int*)   (base + 89661696L);    // NB_S
    int*      tailA = (int*)   (base + 89664824L);    // NB_A

    ushort* xw_item = xw + (long)N_SESS * EMB;  // item half of xw

    // ---- zero bm + tails in one memset (21,924 B) ----
    hipMemsetAsync(bm, 0, 89671076L - 89649152L, stream);
    // ---- PREP: mark needed h1 rows + convW ----
    k_prep<<<MARK_BLKS + 64, 256, 0, stream>>>(batch_idxes, item_idxes, bm, W, Wt);
    // ---- BUILD: strided placement (S, A-filtered) + fused-gather xw GEMM ----
    k_build<<<NBLK_S + NBLK_A + XW_BLKS, 256, 0, stream>>>(
        sess_rows, sess_cols, sess_vals, tailS, edgS,
        A_rows, A_cols, A_vals, tailA, edgA, bm,
        emb_table, item_emb_idxes, Wt, xw_item);
    // ---- spmm1 (reordered): xw[0:N_SESS] = S @ xw_item ----
    k_spmm_sorted<<<NB_S, 512, 0, stream>>>(tailS, edgS, STRIDE_S, xw_item, xw,
                                            nullptr, N_SESS, nullptr);
    // ---- spmm2 + fused bias -> h1 (only needed rows written) ----
    k_spmm_sorted<<<NB_A, 512, 0, stream>>>(tailA, edgA, STRIDE_A, xw, h1,
                                            b, N_TOTAL, bm);
    // ---- score (1D grid, XCD-swizzled, inline hb/hi gather, 256x128 tiles) ----
    k_score_mfma<<<SB_TOT, 512, 0, stream>>>(h1, batch_idxes, item_idxes, out);
}